// Round 5
// baseline (346.232 us; speedup 1.0000x reference)
//
#include <hip/hip_runtime.h>
#include <hip/hip_bf16.h>

// Problem constants
#define NN  50000   // nodes
#define FD  128     // features
#define NE  800000  // external edges
#define NEI 400000  // internal edges
#define NG  64      // graphs

// Per-copy strides (in elements) for XCD-privatized accumulators
#define DEG_STRIDE 50176     // ints  (200704 B per copy)
#define EZ_STRIDE  8192      // floats (32768 B per copy)
#define CNT_STRIDE 64        // ints   (256 B per copy)

typedef short  short8 __attribute__((ext_vector_type(8)));
typedef float  f32x4  __attribute__((ext_vector_type(4)));

union S8 { short8 s; unsigned int u[4]; };

__device__ __forceinline__ unsigned short bf16h(float f) {
  unsigned int u = __float_as_uint(f);
  u += 0x7FFFu + ((u >> 16) & 1u);            // RNE
  return (unsigned short)(u >> 16);
}
__device__ __forceinline__ float bf16tof(unsigned short h) {
  return __uint_as_float(((unsigned int)h) << 16);
}
// packed 2xf32 -> 2xbf16 (v_cvt_pk_bf16_f32): a in low 16, b in high 16
__device__ __forceinline__ unsigned int pk_bf16(float a, float b) {
  __hip_bfloat162 h = __float22bfloat162_rn(make_float2(a, b));
  unsigned int u;
  __builtin_memcpy(&u, &h, 4);
  return u;
}
// fast reciprocal: v_rcp_f32 (~1 ulp) — tolerance is 4.2e-5, plenty of slack
__device__ __forceinline__ float frcp(float x) { return __builtin_amdgcn_rcpf(x); }

// -------------------------------------------------------------------------
// ONE aux dispatch (R11 structure).  Atomic targets XCD-privatized:
// copy = blockIdx & (ncopy-1); round-robin block->XCD dispatch keeps each
// copy (mostly) XCD-local.
// -------------------------------------------------------------------------
#define AB_EXT 391
#define AB_INT 196
#define AB_BAT 13
#define AB_PRE 8

__global__ __launch_bounds__(256) void aux_kernel(
    const int4* __restrict__ ei4, const int4* __restrict__ iei4,
    const int* __restrict__ batch,
    const float* __restrict__ wu_e1, const float* __restrict__ wu_e2,
    const float* __restrict__ wu_i1, const float* __restrict__ wu_i2,
    int* __restrict__ deg_ext, int* __restrict__ deg_int, int* __restrict__ cnt,
    unsigned short* __restrict__ WB, float* __restrict__ wcolp, int ncopy)
{
  __shared__ float WS[64 * 129];
  __shared__ int   hb[64];
  const int b = blockIdx.x, t = threadIdx.x;
  const int cp = b & (ncopy - 1);

  if (b < AB_EXT) {
    int* __restrict__ d = deg_ext + (size_t)cp * DEG_STRIDE;
    const int base = b * 512 + t;
    #pragma unroll
    for (int u = 0; u < 2; ++u) {
      const int i = base + u * 256;
      if (i < NE / 4) {
        const int4 v = ei4[i];
        atomicAdd(&d[v.x], 1);
        atomicAdd(&d[v.y], 1);
        atomicAdd(&d[v.z], 1);
        atomicAdd(&d[v.w], 1);
      }
    }
  } else if (b < AB_EXT + AB_INT) {
    int* __restrict__ d = deg_int + (size_t)cp * DEG_STRIDE;
    const int base = (b - AB_EXT) * 512 + t;
    #pragma unroll
    for (int u = 0; u < 2; ++u) {
      const int i = base + u * 256;
      if (i < NEI / 4) {
        const int4 v = iei4[i];
        atomicAdd(&d[v.x], 1);
        atomicAdd(&d[v.y], 1);
        atomicAdd(&d[v.z], 1);
        atomicAdd(&d[v.w], 1);
      }
    }
  } else if (b < AB_EXT + AB_INT + AB_BAT) {
    if (t < 64) hb[t] = 0;
    __syncthreads();
    const int base = (b - AB_EXT - AB_INT) * 4096 + t;
    for (int u = 0; u < 16; ++u) {
      const int i = base + u * 256;
      if (i < NN) atomicAdd(&hb[batch[i]], 1);
    }
    __syncthreads();
    if (t < 64 && hb[t]) atomicAdd(&cnt[cp * CNT_STRIDE + t], hb[t]);
  } else {
    const int pb = b - AB_EXT - AB_INT - AB_BAT;   // 0..7
    const int c  = pb >> 1;                         // conv 0..3
    const int h  = pb & 1;                          // row half
    const float* wu = (c == 0) ? wu_e1 : (c == 1) ? wu_e2 : (c == 2) ? wu_i1 : wu_i2;
    for (int idx = t; idx < 64 * 129; idx += 256)
      WS[idx] = wu[(size_t)h * 64 * 129 + idx];
    __syncthreads();
    const int lane = t & 63, u = t >> 6;
    const int n = lane & 15, quad = lane >> 4;
    const int ct = 4 * h + u;
    unsigned short* wb = WB + c * 32768;
    #pragma unroll
    for (int kc = 0; kc < 4; ++kc) {
      const int k0 = kc * 32 + quad * 8;
      const float* src = &WS[(u * 16 + n) * 129 + k0];
      short8 hi, lo;
      #pragma unroll
      for (int e = 0; e < 8; ++e) {
        const float v = src[e];
        const unsigned short hh = bf16h(v);
        hi[e] = (short)hh;
        lo[e] = (short)bf16h(v - bf16tof(hh));
      }
      const int fbase = ((ct * 4 + kc) * 2) * 512 + lane * 8;
      *(short8*)&wb[fbase]       = hi;
      *(short8*)&wb[fbase + 512] = lo;
    }
    if (t < 64) wcolp[c * 128 + h * 64 + t] = WS[t * 129 + 128];
  }
}

// -------------------------------------------------------------------------
// Merge of the ncopy privatized degree histograms into ONE array (R12).
// degm layout: [0, DEG_STRIDE) = ext, [DEG_STRIDE, 2*DEG_STRIDE) = int.
// -------------------------------------------------------------------------
__global__ __launch_bounds__(256) void merge_deg_kernel(
    const int* __restrict__ deg_ext, const int* __restrict__ deg_int,
    int* __restrict__ degm, int ncopy)
{
  const int i = blockIdx.x * 256 + threadIdx.x;   // grid covers DEG_STRIDE
  int se = 0, si = 0;
  for (int c = 0; c < ncopy; ++c) {
    se += deg_ext[(size_t)c * DEG_STRIDE + i];
    si += deg_int[(size_t)c * DEG_STRIDE + i];
  }
  degm[i] = se;
  degm[DEG_STRIDE + i] = si;
}

// -------------------------------------------------------------------------
// Fused conv chain.  R13: TILE HALVED for TLP — 32 rows / 256 threads /
// 4 waves; grid 782 -> 1563 (~6 independent blocks/CU, all resident;
// LDS 18.5 KB).  Same total work; twice the independent barrier-groups
// per CU, half the barrier scope and per-block critical path.  Prologue
// reordered: x/deg/batch (HBM/L3-latency) loads issued BEFORE the
// L2-resident B-slice loads.  Everything else identical to R12.
// -------------------------------------------------------------------------
#define ROWS 32

__global__ __launch_bounds__(256, 6) void conv_mfma_kernel(
    const float* __restrict__ x,
    const int* __restrict__ degm,
    const int* __restrict__ batch,
    const unsigned short* __restrict__ WB, const float* __restrict__ wcolp,
    const float* __restrict__ bu_e1, const float* __restrict__ bu_e2,
    const float* __restrict__ bu_i1, const float* __restrict__ bu_i2,
    float* __restrict__ ez_sum, float* __restrict__ iz_sum, int ncopy)
{
  __shared__ unsigned short XT[2][4096];   // A fragments (bf16), 2 x 8 KB
  __shared__ float degsE[ROWS];
  __shared__ float degsI[ROWS];
  __shared__ int   bg[ROWS];
  __shared__ float redA[ROWS * 8];         // [row][wave]: s1e, then s2e
  __shared__ float redB[ROWS * 8];         // [row][wave]: s1i, then s2i

  const int tid  = threadIdx.x;
  const int lane = tid & 63;
  const int w    = tid >> 6;        // wave = column tile 0..3? NO: 4 waves,
                                    // but 8 column-tiles -> w in 0..3 covers
                                    // cols via j below with 2 ct per wave?  —
                                    // we keep 8 col-tiles mapped to 4 waves by
                                    // col-pairing: each wave owns 16 cols via
                                    // (w) and the OTHER 64 cols come from the
                                    // second fragment set.  Simpler: waves own
                                    // ct = w and ct = w+4 (two B-slices).
  const int n    = lane & 15;
  const int q    = lane >> 4;
  const int mbase = blockIdx.x * ROWS;
  const int cp = blockIdx.x & (ncopy - 1);

  // ---- prologue A: issue latency-critical loads first (x, deg, batch)
  // stage x -> bf16 A fragments in XT[0], octet-linear (conflict-free).
  // 512 octets of 16B = 8 KB  (ROWS=32 rows x 128 k x 2B).
  float4 sa[2], sb[2];
  int soct[2];
  #pragma unroll
  for (int u = 0; u < 2; ++u) {
    const int oct  = u * 256 + tid;          // 512 octets
    const int frag = oct >> 6, l = oct & 63; // frag = rt_s*4+kc_s
    const int row  = (frag >> 2) * 16 + (l & 15);
    const int k0   = (frag & 3) * 32 + (l >> 4) * 8;
    const int node = mbase + row;
    soct[u] = oct;
    sa[u] = make_float4(0.f, 0.f, 0.f, 0.f); sb[u] = sa[u];
    if (node < NN) {
      const float* xr = x + (size_t)node * FD + k0;
      sa[u] = *(const float4*)xr;
      sb[u] = *(const float4*)(xr + 4);
    }
  }
  if (tid < ROWS) {
    const int node = mbase + tid;
    const bool v = node < NN;
    const int nc = v ? node : (NN - 1);
    degsE[tid] = v ? (float)degm[node] : 0.f;
    degsI[tid] = v ? (float)degm[DEG_STRIDE + node] : 0.f;
    bg[tid]    = batch[nc];       // clamped: invalid rows inherit last graph
  }

  // ---- prologue B: B-slices (L2-resident WB).  Each wave owns TWO
  // column-tiles: ctA = w (cols 16w..16w+15) and ctB = w+4.
  const int jA = w * 16 + n;            // column for ctA
  const int jB = (w + 4) * 16 + n;      // column for ctB

#define LOADB(CONV, CT, BH, BL) do {                                          \
    const unsigned short* _p = WB + (CONV) * 32768 + ((CT) * 4) * 1024 + lane * 8;\
    _Pragma("unroll")                                                          \
    for (int _kc = 0; _kc < 4; ++_kc) {                                        \
      BH[_kc] = *(const short8*)&_p[_kc * 1024];                               \
      BL[_kc] = *(const short8*)&_p[_kc * 1024 + 512];                         \
    }                                                                          \
  } while (0)

  short8 BEhA[4], BElA[4], BIhA[4], BIlA[4];
  short8 BEhB[4], BElB[4], BIhB[4], BIlB[4];
  LOADB(0, w,     BEhA, BElA);          // ext conv1, ctA
  LOADB(0, w + 4, BEhB, BElB);          // ext conv1, ctB
  LOADB(2, w,     BIhA, BIlA);          // int conv1, ctA
  LOADB(2, w + 4, BIhB, BIlB);          // int conv1, ctB
  const float wcE1A = wcolp[0 * 128 + jA], wcE1B = wcolp[0 * 128 + jB];
  const float wcE2A = wcolp[1 * 128 + jA], wcE2B = wcolp[1 * 128 + jB];
  const float wcI1A = wcolp[2 * 128 + jA], wcI1B = wcolp[2 * 128 + jB];
  const float wcI2A = wcolp[3 * 128 + jA], wcI2B = wcolp[3 * 128 + jB];
  const float bE1A = bu_e1[jA], bE1B = bu_e1[jB];
  const float bE2A = bu_e2[jA], bE2B = bu_e2[jB];
  const float bI1A = bu_i1[jA], bI1B = bu_i1[jB];
  const float bI2A = bu_i2[jA], bI2B = bu_i2[jB];

  // ---- complete x staging
  #pragma unroll
  for (int u = 0; u < 2; ++u) {
    S8 hi;
    hi.u[0] = pk_bf16(sa[u].x, sa[u].y);
    hi.u[1] = pk_bf16(sa[u].z, sa[u].w);
    hi.u[2] = pk_bf16(sb[u].x, sb[u].y);
    hi.u[3] = pk_bf16(sb[u].z, sb[u].w);
    *(short8*)&XT[0][soct[u] * 8] = hi.s;
  }
  __syncthreads();   // ---- barrier 1: A fragments + degs + bg visible

  // ================= conv1: rows 0..31, cols {ctA, ctB} x {E,I} ==========
  // acc layout: [rt][0]=ctA, [rt][1]=ctB with rt in 0..1
  f32x4 aE[2][2], aI[2][2];
  #pragma unroll
  for (int rt = 0; rt < 2; ++rt)
    #pragma unroll
    for (int s = 0; s < 2; ++s) {
      aE[rt][s] = (f32x4){0.f, 0.f, 0.f, 0.f};
      aI[rt][s] = (f32x4){0.f, 0.f, 0.f, 0.f};
    }
  #pragma unroll
  for (int kc = 0; kc < 4; ++kc) {
    #pragma unroll
    for (int rt = 0; rt < 2; ++rt) {
      const short8 Ah = *(const short8*)&XT[0][((rt * 4 + kc) * 64 + lane) * 8];
      f32x4 c;
      c = aE[rt][0];
      c = __builtin_amdgcn_mfma_f32_16x16x32_bf16(Ah, BEhA[kc], c, 0, 0, 0);
      c = __builtin_amdgcn_mfma_f32_16x16x32_bf16(Ah, BElA[kc], c, 0, 0, 0);
      aE[rt][0] = c;
      c = aE[rt][1];
      c = __builtin_amdgcn_mfma_f32_16x16x32_bf16(Ah, BEhB[kc], c, 0, 0, 0);
      c = __builtin_amdgcn_mfma_f32_16x16x32_bf16(Ah, BElB[kc], c, 0, 0, 0);
      aE[rt][1] = c;
      c = aI[rt][0];
      c = __builtin_amdgcn_mfma_f32_16x16x32_bf16(Ah, BIhA[kc], c, 0, 0, 0);
      c = __builtin_amdgcn_mfma_f32_16x16x32_bf16(Ah, BIlA[kc], c, 0, 0, 0);
      aI[rt][0] = c;
      c = aI[rt][1];
      c = __builtin_amdgcn_mfma_f32_16x16x32_bf16(Ah, BIhB[kc], c, 0, 0, 0);
      c = __builtin_amdgcn_mfma_f32_16x16x32_bf16(Ah, BIlB[kc], c, 0, 0, 0);
      aI[rt][1] = c;
    }
  }

  // ---- epilogue1: E1 = exp(leaky(acc + b + deg*wc)), f32
  #pragma unroll
  for (int rt = 0; rt < 2; ++rt) {
    const float4 dE = *(const float4*)&degsE[rt * 16 + 4 * q];
    const float4 dI = *(const float4*)&degsI[rt * 16 + 4 * q];
    const float dEv[4] = {dE.x, dE.y, dE.z, dE.w};
    const float dIv[4] = {dI.x, dI.y, dI.z, dI.w};
    #pragma unroll
    for (int r = 0; r < 4; ++r) {
      float v;
      v = aE[rt][0][r] + bE1A + dEv[r] * wcE1A; v = fmaxf(v, 0.01f * v); aE[rt][0][r] = __expf(v);
      v = aE[rt][1][r] + bE1B + dEv[r] * wcE1B; v = fmaxf(v, 0.01f * v); aE[rt][1][r] = __expf(v);
      v = aI[rt][0][r] + bI1A + dIv[r] * wcI1A; v = fmaxf(v, 0.01f * v); aI[rt][0][r] = __expf(v);
      v = aI[rt][1][r] + bI1B + dIv[r] * wcI1B; v = fmaxf(v, 0.01f * v); aI[rt][1][r] = __expf(v);
    }
  }

  // ---- s1 partials: row-sum over this wave's 32 cols (ctA+ctB)
  #pragma unroll
  for (int rt = 0; rt < 2; ++rt) {
    #pragma unroll
    for (int r = 0; r < 4; ++r) {
      float te = aE[rt][0][r] + aE[rt][1][r];
      float ti = aI[rt][0][r] + aI[rt][1][r];
      te += __shfl_xor(te, 1); ti += __shfl_xor(ti, 1);
      te += __shfl_xor(te, 2); ti += __shfl_xor(ti, 2);
      te += __shfl_xor(te, 4); ti += __shfl_xor(ti, 4);
      te += __shfl_xor(te, 8); ti += __shfl_xor(ti, 8);
      if (n == 0) {
        redA[(rt * 16 + q * 4 + r) * 8 + w] = te;   // waves write slots 0..3
        redB[(rt * 16 + q * 4 + r) * 8 + w] = ti;
      }
    }
  }
  if (tid < ROWS * 2) {   // zero unused wave slots 4..7 (first block reuse)
    redA[(tid >> 1) * 8 + 4 + (tid & 1) * 2] = 0.f;
    redA[(tid >> 1) * 8 + 5 + (tid & 1) * 2] = 0.f;
    redB[(tid >> 1) * 8 + 4 + (tid & 1) * 2] = 0.f;
    redB[(tid >> 1) * 8 + 5 + (tid & 1) * 2] = 0.f;
  }

  // ---- pack E1 to bf16 pairs (regs); reload B for conv2
  unsigned int pE[2][2][2], pI[2][2][2];
  #pragma unroll
  for (int rt = 0; rt < 2; ++rt)
    #pragma unroll
    for (int s = 0; s < 2; ++s) {
      pE[rt][s][0] = pk_bf16(aE[rt][s][0], aE[rt][s][1]);
      pE[rt][s][1] = pk_bf16(aE[rt][s][2], aE[rt][s][3]);
      pI[rt][s][0] = pk_bf16(aI[rt][s][0], aI[rt][s][1]);
      pI[rt][s][1] = pk_bf16(aI[rt][s][2], aI[rt][s][3]);
    }
  LOADB(1, w,     BEhA, BElA);          // ext conv2
  LOADB(1, w + 4, BEhB, BElB);
  LOADB(3, w,     BIhA, BIlA);          // int conv2
  LOADB(3, w + 4, BIhB, BIlB);

  // ---- write E1e -> XT[1] in A-fragment order.
  // col j -> kc' = j>>5, qk' = ((j>>4)&1)*2 + (n>>3), elem = n&7
  #pragma unroll
  for (int rt = 0; rt < 2; ++rt)
    #pragma unroll
    for (int s = 0; s < 2; ++s) {
      const int ct = w + s * 4;
      const int ib = ((rt * 4 + (ct >> 1)) * 64 + ((ct & 1) * 2 + (n >> 3)) * 16 + q * 4) * 8 + (n & 7);
      XT[1][ib]      = (unsigned short)(pE[rt][s][0] & 0xFFFFu);
      XT[1][ib + 8]  = (unsigned short)(pE[rt][s][0] >> 16);
      XT[1][ib + 16] = (unsigned short)(pE[rt][s][1] & 0xFFFFu);
      XT[1][ib + 24] = (unsigned short)(pE[rt][s][1] >> 16);
    }
  __syncthreads();   // ---- barrier 2: XT1 + s1 partials visible

  // ---- write E1i -> XT[0] (XT0 conv1-reads done)
  #pragma unroll
  for (int rt = 0; rt < 2; ++rt)
    #pragma unroll
    for (int s = 0; s < 2; ++s) {
      const int ct = w + s * 4;
      const int ib = ((rt * 4 + (ct >> 1)) * 64 + ((ct & 1) * 2 + (n >> 3)) * 16 + q * 4) * 8 + (n & 7);
      XT[0][ib]      = (unsigned short)(pI[rt][s][0] & 0xFFFFu);
      XT[0][ib + 8]  = (unsigned short)(pI[rt][s][0] >> 16);
      XT[0][ib + 16] = (unsigned short)(pI[rt][s][1] & 0xFFFFu);
      XT[0][ib + 24] = (unsigned short)(pI[rt][s][1] >> 16);
    }

  // ---- row-owned s1 inverses: lane ℓ&31 owns row ℓ&31
  float s1iE, s1iI;
  {
    const int rl = (lane & 31) * 8;
    const f32x4 a0 = *(const f32x4*)&redA[rl];
    s1iE = frcp((a0[0] + a0[1]) + (a0[2] + a0[3]));
    const f32x4 b0 = *(const f32x4*)&redB[rl];
    s1iI = frcp((b0[0] + b0[1]) + (b0[2] + b0[3]));
  }

  // ================= conv2-ext from XT[1] =================
  f32x4 cE[2][2], cI[2][2];
  #pragma unroll
  for (int rt = 0; rt < 2; ++rt)
    #pragma unroll
    for (int s = 0; s < 2; ++s) cE[rt][s] = (f32x4){0.f, 0.f, 0.f, 0.f};
  #pragma unroll
  for (int kc = 0; kc < 4; ++kc) {
    #pragma unroll
    for (int rt = 0; rt < 2; ++rt) {
      const short8 Ah = *(const short8*)&XT[1][((rt * 4 + kc) * 64 + lane) * 8];
      f32x4 c;
      c = cE[rt][0];
      c = __builtin_amdgcn_mfma_f32_16x16x32_bf16(Ah, BEhA[kc], c, 0, 0, 0);
      c = __builtin_amdgcn_mfma_f32_16x16x32_bf16(Ah, BElA[kc], c, 0, 0, 0);
      cE[rt][0] = c;
      c = cE[rt][1];
      c = __builtin_amdgcn_mfma_f32_16x16x32_bf16(Ah, BEhB[kc], c, 0, 0, 0);
      c = __builtin_amdgcn_mfma_f32_16x16x32_bf16(Ah, BElB[kc], c, 0, 0, 0);
      cE[rt][1] = c;
    }
  }
  __syncthreads();   // ---- barrier 3: E1i visible; redA/redB s1-reads done

  // ================= conv2-int from XT[0] =================
  #pragma unroll
  for (int rt = 0; rt < 2; ++rt)
    #pragma unroll
    for (int s = 0; s < 2; ++s) cI[rt][s] = (f32x4){0.f, 0.f, 0.f, 0.f};
  #pragma unroll
  for (int kc = 0; kc < 4; ++kc) {
    #pragma unroll
    for (int rt = 0; rt < 2; ++rt) {
      const short8 Ah = *(const short8*)&XT[0][((rt * 4 + kc) * 64 + lane) * 8];
      f32x4 c;
      c = cI[rt][0];
      c = __builtin_amdgcn_mfma_f32_16x16x32_bf16(Ah, BIhA[kc], c, 0, 0, 0);
      c = __builtin_amdgcn_mfma_f32_16x16x32_bf16(Ah, BIlA[kc], c, 0, 0, 0);
      cI[rt][0] = c;
      c = cI[rt][1];
      c = __builtin_amdgcn_mfma_f32_16x16x32_bf16(Ah, BIhB[kc], c, 0, 0, 0);
      c = __builtin_amdgcn_mfma_f32_16x16x32_bf16(Ah, BIlB[kc], c, 0, 0, 0);
      cI[rt][1] = c;
    }
  }

  // ---- epilogue2: logits = U2*inv_s1 + b + deg*wc; E2 = exp(leaky(.));
  //      s2 partials -> redA/redB (safe after b3)
  #pragma unroll
  for (int rt = 0; rt < 2; ++rt) {
    const float4 dE = *(const float4*)&degsE[rt * 16 + 4 * q];
    const float4 dI = *(const float4*)&degsI[rt * 16 + 4 * q];
    const float dEv[4] = {dE.x, dE.y, dE.z, dE.w};
    const float dIv[4] = {dI.x, dI.y, dI.z, dI.w};
    #pragma unroll
    for (int r = 0; r < 4; ++r) {
      const int row = rt * 16 + q * 4 + r;
      const float i1e = __shfl(s1iE, row);
      const float i1i = __shfl(s1iI, row);
      float v;
      v = cE[rt][0][r] * i1e + bE2A + dEv[r] * wcE2A; v = fmaxf(v, 0.01f * v); cE[rt][0][r] = __expf(v);
      v = cE[rt][1][r] * i1e + bE2B + dEv[r] * wcE2B; v = fmaxf(v, 0.01f * v); cE[rt][1][r] = __expf(v);
      v = cI[rt][0][r] * i1i + bI2A + dIv[r] * wcI2A; v = fmaxf(v, 0.01f * v); cI[rt][0][r] = __expf(v);
      v = cI[rt][1][r] * i1i + bI2B + dIv[r] * wcI2B; v = fmaxf(v, 0.01f * v); cI[rt][1][r] = __expf(v);
    }
    #pragma unroll
    for (int r = 0; r < 4; ++r) {
      float te = cE[rt][0][r] + cE[rt][1][r];
      float ti = cI[rt][0][r] + cI[rt][1][r];
      te += __shfl_xor(te, 1); ti += __shfl_xor(ti, 1);
      te += __shfl_xor(te, 2); ti += __shfl_xor(ti, 2);
      te += __shfl_xor(te, 4); ti += __shfl_xor(ti, 4);
      te += __shfl_xor(te, 8); ti += __shfl_xor(ti, 8);
      if (n == 0) {
        redA[(rt * 16 + q * 4 + r) * 8 + w] = te;
        redB[(rt * 16 + q * 4 + r) * 8 + w] = ti;
      }
    }
  }
  __syncthreads();   // ---- barrier 4: s2 partials visible

  // ---- row-owned s2 inverses + normalize
  float s2iE, s2iI;
  {
    const int rl = (lane & 31) * 8;
    const f32x4 a0 = *(const f32x4*)&redA[rl];
    s2iE = frcp((a0[0] + a0[1]) + (a0[2] + a0[3]));
    const f32x4 b0 = *(const f32x4*)&redB[rl];
    s2iI = frcp((b0[0] + b0[1]) + (b0[2] + b0[3]));
  }
  #pragma unroll
  for (int rt = 0; rt < 2; ++rt) {
    #pragma unroll
    for (int r = 0; r < 4; ++r) {
      const int row = rt * 16 + q * 4 + r;
      const float i2e = __shfl(s2iE, row);
      const float i2i = __shfl(s2iI, row);
      cE[rt][0][r] *= i2e; cE[rt][1][r] *= i2e;
      cI[rt][0][r] *= i2i; cI[rt][1][r] *= i2i;
    }
  }

  // ---- scatter into XCD-private per-graph sums (masked per-graph reduce)
  {
    float* __restrict__ ezp = ez_sum + (size_t)cp * EZ_STRIDE;
    float* __restrict__ izp = iz_sum + (size_t)cp * EZ_STRIDE;

    if (mbase + ROWS - 1 >= NN) {   // zero out-of-range rows (last block)
      #pragma unroll
      for (int rt = 0; rt < 2; ++rt)
        #pragma unroll
        for (int r = 0; r < 4; ++r) {
          const int row = rt * 16 + q * 4 + r;
          if (mbase + row >= NN) {
            cE[rt][0][r] = 0.f; cE[rt][1][r] = 0.f;
            cI[rt][0][r] = 0.f; cI[rt][1][r] = 0.f;
          }
        }
    }

    const int g0 = bg[0], g1 = bg[ROWS - 1];
    for (int g = g0; g <= g1; ++g) {
      float seA = 0.f, siA = 0.f, seB = 0.f, siB = 0.f;
      const bool one = (g0 == g1);
      #pragma unroll
      for (int rt = 0; rt < 2; ++rt)
        #pragma unroll
        for (int r = 0; r < 4; ++r) {
          const int row = rt * 16 + q * 4 + r;
          const bool m = one || (bg[row] == g);
          seA += m ? cE[rt][0][r] : 0.f;
          seB += m ? cE[rt][1][r] : 0.f;
          siA += m ? cI[rt][0][r] : 0.f;
          siB += m ? cI[rt][1][r] : 0.f;
        }
      seA += __shfl_xor(seA, 16); siA += __shfl_xor(siA, 16);
      seB += __shfl_xor(seB, 16); siB += __shfl_xor(siB, 16);
      seA += __shfl_xor(seA, 32); siA += __shfl_xor(siA, 32);
      seB += __shfl_xor(seB, 32); siB += __shfl_xor(siB, 32);
      if (q == 0) {
        atomicAdd(&ezp[g * FD + jA], seA);
        atomicAdd(&ezp[g * FD + jB], seB);
        atomicAdd(&izp[g * FD + jA], siA);
        atomicAdd(&izp[g * FD + jB], siB);
      }
    }
  }
#undef LOADB
}

// -------------------------------------------------------------------------
// Final MLP: 64 blocks (one per graph) x 128 threads.  Sums ncopy
// XCD-private partials for z and cnt.
// -------------------------------------------------------------------------
__global__ __launch_bounds__(128) void fc_kernel(
    const float* __restrict__ ez_sum, const float* __restrict__ iz_sum,
    const int* __restrict__ cnt,
    const float* __restrict__ fc1_w, const float* __restrict__ fc1_b,
    const float* __restrict__ fc2_w, const float* __restrict__ fc2_b,
    float* __restrict__ out, int ncopy)
{
  __shared__ float z[256];
  __shared__ float red2[2];
  const int g = blockIdx.x, t = threadIdx.x;
  int cc = 0;
  float se = 0.f, si = 0.f;
  for (int c = 0; c < ncopy; ++c) {
    cc += cnt[c * CNT_STRIDE + g];
    se += ez_sum[(size_t)c * EZ_STRIDE + g * 128 + t];
    si += iz_sum[(size_t)c * EZ_STRIDE + g * 128 + t];
  }
  const float denom = fmaxf((float)cc, 1.0f);
  z[t]       = se / denom;
  z[128 + t] = si / denom;
  __syncthreads();

  const float* wr = fc1_w + (size_t)t * 256;
  float a = fc1_b[t];
  #pragma unroll 4
  for (int c = 0; c < 256; c += 4) {
    const float4 wv = *(const float4*)(wr + c);
    a += wv.x * z[c] + wv.y * z[c + 1] + wv.z * z[c + 2] + wv.w * z[c + 3];
  }
  a = fmaxf(a, 0.f) * fc2_w[t];
  a += __shfl_xor(a, 1);
  a += __shfl_xor(a, 2);
  a += __shfl_xor(a, 4);
  a += __shfl_xor(a, 8);
  a += __shfl_xor(a, 16);
  a += __shfl_xor(a, 32);
  if ((t & 63) == 0) red2[t >> 6] = a;
  __syncthreads();
  if (t == 0) out[g] = red2[0] + red2[1] + fc2_b[0];
}

// -------------------------------------------------------------------------
extern "C" void kernel_launch(void* const* d_in, const int* in_sizes, int n_in,
                              void* d_out, int out_size, void* d_ws, size_t ws_size,
                              hipStream_t stream) {
  const float* x     = (const float*)d_in[0];
  const int4*  ei4   = (const int4*) d_in[1];   // [2,E]: first E = sources
  const int4*  iei4  = (const int4*) d_in[3];
  const int*   batch = (const int*)  d_in[5];
  const float* wu_e1 = (const float*)d_in[8];
  const float* bu_e1 = (const float*)d_in[9];
  const float* wu_e2 = (const float*)d_in[12];
  const float* bu_e2 = (const float*)d_in[13];
  const float* wu_i1 = (const float*)d_in[16];
  const float* bu_i1 = (const float*)d_in[17];
  const float* wu_i2 = (const float*)d_in[20];
  const float* bu_i2 = (const float*)d_in[21];
  const float* fc1_w = (const float*)d_in[22];
  const float* fc1_b = (const float*)d_in[23];
  const float* fc2_w = (const float*)d_in[24];
  const float* fc2_b = (const float*)d_in[25];

  // Layout: [ncopy x deg_ext][ncopy x deg_int][ncopy x ez][ncopy x iz]
  //         [ncopy x cnt] | (zeroed up to here) | [degm 2x][WB][wcolp]
  const size_t need8 = 8ull * (2 * 200704 + 2 * 32768 + 256)
                     + 2 * 200704 + 262144 + 2048;
  const int ncopy = (ws_size >= need8) ? 8 : 1;

  char* ws = (char*)d_ws;
  size_t off = 0;
  int*   deg_ext = (int*)(ws + off);  off += (size_t)ncopy * 200704;
  int*   deg_int = (int*)(ws + off);  off += (size_t)ncopy * 200704;
  float* ez      = (float*)(ws + off); off += (size_t)ncopy * 32768;
  float* iz      = (float*)(ws + off); off += (size_t)ncopy * 32768;
  int*   cnt     = (int*)(ws + off);  off += (size_t)ncopy * 256;
  const size_t zero_bytes = off;
  int*   degm    = (int*)(ws + off);  off += 2 * 200704;
  unsigned short* WB = (unsigned short*)(ws + off); off += 262144;
  float* wcolp   = (float*)(ws + off); off += 2048;

  hipMemsetAsync(d_ws, 0, zero_bytes, stream);

  aux_kernel<<<AB_EXT + AB_INT + AB_BAT + AB_PRE, 256, 0, stream>>>(
      ei4, iei4, batch, wu_e1, wu_e2, wu_i1, wu_i2,
      deg_ext, deg_int, cnt, WB, wcolp, ncopy);

  merge_deg_kernel<<<DEG_STRIDE / 256, 256, 0, stream>>>(
      deg_ext, deg_int, degm, ncopy);

  conv_mfma_kernel<<<dim3((NN + ROWS - 1) / ROWS), 256, 0, stream>>>(
      x, degm, batch, WB, wcolp,
      bu_e1, bu_e2, bu_i1, bu_i2, ez, iz, ncopy);

  fc_kernel<<<NG, 128, 0, stream>>>(ez, iz, cnt, fc1_w, fc1_b, fc2_w, fc2_b,
                                    (float*)d_out, ncopy);
}

// Round 6
// 227.512 us; speedup vs baseline: 1.5218x; 1.5218x over previous
//
#include <hip/hip_runtime.h>
#include <hip/hip_bf16.h>
#include <hip/hip_cooperative_groups.h>

namespace cg = cooperative_groups;

// Problem constants
#define NN  50000   // nodes
#define FD  128     // features
#define NE  800000  // external edges
#define NEI 400000  // internal edges
#define NG  64      // graphs

// Per-copy strides (in elements) for XCD-privatized accumulators
#define DEG_STRIDE 50176     // ints  (200704 B per copy)
#define EZ_STRIDE  8192      // floats (32768 B per copy)
#define CNT_STRIDE 64        // ints   (256 B per copy)

#define NB ((NN + 63) / 64)  // 782 conv blocks

typedef short  short8 __attribute__((ext_vector_type(8)));
typedef float  f32x4  __attribute__((ext_vector_type(4)));

union S8 { short8 s; unsigned int u[4]; };

__device__ __forceinline__ unsigned short bf16h(float f) {
  unsigned int u = __float_as_uint(f);
  u += 0x7FFFu + ((u >> 16) & 1u);            // RNE
  return (unsigned short)(u >> 16);
}
__device__ __forceinline__ float bf16tof(unsigned short h) {
  return __uint_as_float(((unsigned int)h) << 16);
}
__device__ __forceinline__ unsigned int pk_bf16(float a, float b) {
  __hip_bfloat162 h = __float22bfloat162_rn(make_float2(a, b));
  unsigned int u;
  __builtin_memcpy(&u, &h, 4);
  return u;
}
__device__ __forceinline__ float frcp(float x) { return __builtin_amdgcn_rcpf(x); }

// =========================================================================
// FUSED cooperative kernel (R14): aux-histogram + W-prep + conv chain.
// Phase A: edge-degree histogram slices (XCD-privatized atomics) + x staging;
//          blocks 0..7 also run W->B-fragment prep (LDS overlay on XT).
// threadfence + grid.sync  (release; WB/wcolp first-touch-read after).
// Phase B: R12 conv body verbatim; degs = 8-copy parallel sum; batch
//          histogram via sorted-run ballot on bg[] (~2 atomics/block).
// LDS 37888 B -> 4 blocks/CU -> 1024 resident >= 782.  VGPR ~64 (R12).
// =========================================================================
__global__ __launch_bounds__(512, 4) void fused_kernel(
    const float* __restrict__ x,
    const int4* __restrict__ ei4, const int4* __restrict__ iei4,
    const int* __restrict__ batch,
    const float* __restrict__ wu_e1, const float* __restrict__ wu_e2,
    const float* __restrict__ wu_i1, const float* __restrict__ wu_i2,
    int* __restrict__ deg_ext, int* __restrict__ deg_int, int* __restrict__ cnt,
    unsigned short* __restrict__ WB, float* __restrict__ wcolp,
    const float* __restrict__ bu_e1, const float* __restrict__ bu_e2,
    const float* __restrict__ bu_i1, const float* __restrict__ bu_i2,
    float* __restrict__ ez_sum, float* __restrict__ iz_sum, int ncopy)
{
  // ---- shared overlay: WS (phase A, blocks 0..7) aliases XT (phase B)
  __shared__ __align__(16) char SMEM[37888];
  unsigned short* XT0 = (unsigned short*)SMEM;            // 16384 B
  unsigned short* XT1 = (unsigned short*)(SMEM + 16384);  // 16384 B
  float* degsE = (float*)(SMEM + 33024);                  // 256 B
  float* degsI = (float*)(SMEM + 33280);                  // 256 B
  int*   bg    = (int*)  (SMEM + 33536);                  // 256 B
  float* redA  = (float*)(SMEM + 33792);                  // 2048 B
  float* redB  = (float*)(SMEM + 35840);                  // 2048 B
  float* WS    = (float*)SMEM;                            // 33024 B (aliases XT)

  const int tid  = threadIdx.x;
  const int lane = tid & 63;
  const int w    = tid >> 6;        // wave = column tile 0..7
  const int n    = lane & 15;
  const int q    = lane >> 4;
  const int b    = blockIdx.x;
  const int mbase = b * 64;
  const int j = w * 16 + n;
  const int cp = b & (ncopy - 1);

  // ================= PHASE A =================
  // edge-degree histogram slices (global atomics, no LDS dependence)
  if (tid < 256) {
    const int i = b * 256 + tid;                   // ext: 782*256 >= 200000
    if (i < NE / 4) {
      int* __restrict__ d = deg_ext + (size_t)cp * DEG_STRIDE;
      const int4 v = ei4[i];
      atomicAdd(&d[v.x], 1);
      atomicAdd(&d[v.y], 1);
      atomicAdd(&d[v.z], 1);
      atomicAdd(&d[v.w], 1);
    }
  } else if (tid < 384) {
    const int i = b * 128 + (tid - 256);           // int: 782*128 >= 100000
    if (i < NEI / 4) {
      int* __restrict__ d = deg_int + (size_t)cp * DEG_STRIDE;
      const int4 v = iei4[i];
      atomicAdd(&d[v.x], 1);
      atomicAdd(&d[v.y], 1);
      atomicAdd(&d[v.z], 1);
      atomicAdd(&d[v.w], 1);
    }
  }

  // W -> B-fragment prep (blocks 0..7 only; uses WS which aliases XT)
  if (b < 8) {
    const int c = b >> 1, h = b & 1;
    const float* wu = (c == 0) ? wu_e1 : (c == 1) ? wu_e2 : (c == 2) ? wu_i1 : wu_i2;
    for (int idx = tid; idx < 64 * 129; idx += 512)
      WS[idx] = wu[(size_t)h * 64 * 129 + idx];
    __syncthreads();
    if (tid < 256) {
      const int l2 = tid & 63, u = tid >> 6;      // u 0..3
      const int n2 = l2 & 15, quad = l2 >> 4;
      const int ct = 4 * h + u;
      unsigned short* wb = WB + c * 32768;
      #pragma unroll
      for (int kc = 0; kc < 4; ++kc) {
        const int k0 = kc * 32 + quad * 8;
        const float* src = &WS[(u * 16 + n2) * 129 + k0];
        short8 hi, lo;
        #pragma unroll
        for (int e = 0; e < 8; ++e) {
          const float v = src[e];
          const unsigned short hh = bf16h(v);
          hi[e] = (short)hh;
          lo[e] = (short)bf16h(v - bf16tof(hh));
        }
        const int fbase = ((ct * 4 + kc) * 2) * 512 + l2 * 8;
        *(short8*)&wb[fbase]       = hi;
        *(short8*)&wb[fbase + 512] = lo;
      }
    }
    if (tid < 64) wcolp[c * 128 + h * 64 + tid] = WS[tid * 129 + 128];
    __syncthreads();   // WS reads done -> safe to overwrite with XT staging
  }

  // stage x -> bf16 A fragments in XT0, octet-linear (conflict-free)
  #pragma unroll
  for (int u = 0; u < 2; ++u) {
    const int oct  = u * 512 + tid;          // 1024 octets
    const int frag = oct >> 6, l = oct & 63;
    const int row  = (frag >> 2) * 16 + (l & 15);
    const int k0   = (frag & 3) * 32 + (l >> 4) * 8;
    const int node = mbase + row;
    float4 a = make_float4(0.f, 0.f, 0.f, 0.f), bb = a;
    if (node < NN) {
      const float* xr = x + (size_t)node * FD + k0;
      a  = *(const float4*)xr;
      bb = *(const float4*)(xr + 4);
    }
    S8 hi;
    hi.u[0] = pk_bf16(a.x, a.y);
    hi.u[1] = pk_bf16(a.z, a.w);
    hi.u[2] = pk_bf16(bb.x, bb.y);
    hi.u[3] = pk_bf16(bb.z, bb.w);
    *(short8*)&XT0[oct * 8] = hi.s;
  }

  // release all phase-A global writes, then grid-wide barrier
  __threadfence();
  cg::this_grid().sync();

  // ================= PHASE B (R12 conv body) =================
  // degs: parallel 8-copy sum (512 threads = 64 nodes x 8 copies)
  {
    const int node = tid >> 3, c = tid & 7;
    const int gn = mbase + node;
    float pe = 0.f, pi = 0.f;
    if (gn < NN && c < ncopy) {
      pe = (float)deg_ext[(size_t)c * DEG_STRIDE + gn];
      pi = (float)deg_int[(size_t)c * DEG_STRIDE + gn];
    }
    #pragma unroll
    for (int s = 1; s < 8; s <<= 1) { pe += __shfl_xor(pe, s); pi += __shfl_xor(pi, s); }
    if (c == 0) { degsE[node] = pe; degsI[node] = pi; }
    if (tid < 64) bg[tid] = batch[min(mbase + tid, NN - 1)];
  }
  __syncthreads();   // ---- barrier 1: A fragments + degs + bg visible

  // batch histogram via sorted-run ballot (wave 0 only, ~2 atomics/block)
  if (w == 0) {
    const int node = mbase + lane;
    const int nvalid = min(64, NN - mbase);
    const bool valid = lane < nvalid;
    const int v = bg[lane];
    const int pv = __shfl_up(v, 1);
    bool isb = false;
    if (valid) {
      if (lane == 0) isb = (node == 0) || (batch[node - 1] != v);
      else           isb = (pv != v);
    }
    const unsigned long long mb = __ballot(isb);
    if (isb) {
      const unsigned long long rest = (lane < 63) ? (mb >> (lane + 1)) : 0ull;
      const int nb2 = rest ? (lane + __ffsll((long long)rest)) : nvalid;
      atomicAdd(&cnt[cp * CNT_STRIDE + v], nb2 - lane);
    }
  }

#define LOADB(CONV, BH, BL) do {                                              \
    const unsigned short* _p = WB + (CONV) * 32768 + (w * 4) * 1024 + lane * 8;\
    _Pragma("unroll")                                                          \
    for (int _kc = 0; _kc < 4; ++_kc) {                                        \
      BH[_kc] = *(const short8*)&_p[_kc * 1024];                               \
      BL[_kc] = *(const short8*)&_p[_kc * 1024 + 512];                         \
    }                                                                          \
  } while (0)

  short8 BEh[4], BEl[4], BIh[4], BIl[4];
  LOADB(0, BEh, BEl);               // ext conv1
  LOADB(2, BIh, BIl);               // int conv1
  const float wcE1 = wcolp[0 * 128 + j], wcE2 = wcolp[1 * 128 + j];
  const float wcI1 = wcolp[2 * 128 + j], wcI2 = wcolp[3 * 128 + j];
  const float bE1 = bu_e1[j], bE2 = bu_e2[j];
  const float bI1 = bu_i1[j], bI2 = bu_i2[j];

  // ================= conv1, both chains share each A read ================
  f32x4 aE[4], aI[4];
  #pragma unroll
  for (int rt = 0; rt < 4; ++rt) {
    aE[rt] = (f32x4){0.f, 0.f, 0.f, 0.f};
    aI[rt] = (f32x4){0.f, 0.f, 0.f, 0.f};
  }
  #pragma unroll
  for (int kc = 0; kc < 4; ++kc) {
    #pragma unroll
    for (int rt = 0; rt < 4; ++rt) {
      const short8 Ah = *(const short8*)&XT0[((rt * 4 + kc) * 64 + lane) * 8];
      f32x4 ce = aE[rt];
      ce = __builtin_amdgcn_mfma_f32_16x16x32_bf16(Ah, BEh[kc], ce, 0, 0, 0);
      ce = __builtin_amdgcn_mfma_f32_16x16x32_bf16(Ah, BEl[kc], ce, 0, 0, 0);
      aE[rt] = ce;
      f32x4 ci = aI[rt];
      ci = __builtin_amdgcn_mfma_f32_16x16x32_bf16(Ah, BIh[kc], ci, 0, 0, 0);
      ci = __builtin_amdgcn_mfma_f32_16x16x32_bf16(Ah, BIl[kc], ci, 0, 0, 0);
      aI[rt] = ci;
    }
  }

  // ---- epilogue1 (both chains): E1 = exp(leaky(acc + b + deg*wc)), f32
  #pragma unroll
  for (int rt = 0; rt < 4; ++rt) {
    const float4 dE = *(const float4*)&degsE[rt * 16 + 4 * q];
    const float4 dI = *(const float4*)&degsI[rt * 16 + 4 * q];
    const float dEv[4] = {dE.x, dE.y, dE.z, dE.w};
    const float dIv[4] = {dI.x, dI.y, dI.z, dI.w};
    #pragma unroll
    for (int r = 0; r < 4; ++r) {
      float ve = aE[rt][r] + bE1 + dEv[r] * wcE1;
      ve = fmaxf(ve, 0.01f * ve);
      aE[rt][r] = __expf(ve);
      float vi = aI[rt][r] + bI1 + dIv[r] * wcI1;
      vi = fmaxf(vi, 0.01f * vi);
      aI[rt][r] = __expf(vi);
    }
  }

  // ---- s1 partials (exact f32)
  #pragma unroll
  for (int rt = 0; rt < 4; ++rt) {
    #pragma unroll
    for (int r = 0; r < 4; ++r) {
      float te = aE[rt][r], ti = aI[rt][r];
      te += __shfl_xor(te, 1); ti += __shfl_xor(ti, 1);
      te += __shfl_xor(te, 2); ti += __shfl_xor(ti, 2);
      te += __shfl_xor(te, 4); ti += __shfl_xor(ti, 4);
      te += __shfl_xor(te, 8); ti += __shfl_xor(ti, 8);
      if (n == 0) {
        redA[(rt * 16 + q * 4 + r) * 8 + w] = te;
        redB[(rt * 16 + q * 4 + r) * 8 + w] = ti;
      }
    }
  }

  // ---- pack E1 to bf16 pairs; reload B for conv2
  unsigned int pE[4][2], pI[4][2];
  #pragma unroll
  for (int rt = 0; rt < 4; ++rt) {
    pE[rt][0] = pk_bf16(aE[rt][0], aE[rt][1]);
    pE[rt][1] = pk_bf16(aE[rt][2], aE[rt][3]);
    pI[rt][0] = pk_bf16(aI[rt][0], aI[rt][1]);
    pI[rt][1] = pk_bf16(aI[rt][2], aI[rt][3]);
  }
  LOADB(1, BEh, BEl);               // ext conv2
  LOADB(3, BIh, BIl);               // int conv2

  // ---- write E1e -> XT1 in A-fragment order
  #pragma unroll
  for (int rt = 0; rt < 4; ++rt) {
    const int ib = ((rt * 4 + (w >> 1)) * 64 + ((w & 1) * 2 + (n >> 3)) * 16 + q * 4) * 8 + (n & 7);
    XT1[ib]      = (unsigned short)(pE[rt][0] & 0xFFFFu);
    XT1[ib + 8]  = (unsigned short)(pE[rt][0] >> 16);
    XT1[ib + 16] = (unsigned short)(pE[rt][1] & 0xFFFFu);
    XT1[ib + 24] = (unsigned short)(pE[rt][1] >> 16);
  }
  __syncthreads();   // ---- barrier 2: XT1 + s1 partials visible

  // ---- write E1i -> XT0 (conv1 reads done)
  #pragma unroll
  for (int rt = 0; rt < 4; ++rt) {
    const int ib = ((rt * 4 + (w >> 1)) * 64 + ((w & 1) * 2 + (n >> 3)) * 16 + q * 4) * 8 + (n & 7);
    XT0[ib]      = (unsigned short)(pI[rt][0] & 0xFFFFu);
    XT0[ib + 8]  = (unsigned short)(pI[rt][0] >> 16);
    XT0[ib + 16] = (unsigned short)(pI[rt][1] & 0xFFFFu);
    XT0[ib + 24] = (unsigned short)(pI[rt][1] >> 16);
  }

  // ---- row-owned s1 inverses
  float s1iE, s1iI;
  {
    const f32x4 a0 = *(const f32x4*)&redA[lane * 8];
    const f32x4 a1 = *(const f32x4*)&redA[lane * 8 + 4];
    s1iE = frcp(((a0[0] + a0[1]) + (a0[2] + a0[3])) + ((a1[0] + a1[1]) + (a1[2] + a1[3])));
    const f32x4 b0 = *(const f32x4*)&redB[lane * 8];
    const f32x4 b1 = *(const f32x4*)&redB[lane * 8 + 4];
    s1iI = frcp(((b0[0] + b0[1]) + (b0[2] + b0[3])) + ((b1[0] + b1[1]) + (b1[2] + b1[3])));
  }

  // ================= conv2-ext from XT1 =================
  f32x4 cE[4], cI[4];
  #pragma unroll
  for (int rt = 0; rt < 4; ++rt) cE[rt] = (f32x4){0.f, 0.f, 0.f, 0.f};
  #pragma unroll
  for (int kc = 0; kc < 4; ++kc) {
    #pragma unroll
    for (int rt = 0; rt < 4; ++rt) {
      const short8 Ah = *(const short8*)&XT1[((rt * 4 + kc) * 64 + lane) * 8];
      f32x4 c = cE[rt];
      c = __builtin_amdgcn_mfma_f32_16x16x32_bf16(Ah, BEh[kc], c, 0, 0, 0);
      c = __builtin_amdgcn_mfma_f32_16x16x32_bf16(Ah, BEl[kc], c, 0, 0, 0);
      cE[rt] = c;
    }
  }
  __syncthreads();   // ---- barrier 3: E1i visible; s1-reads done

  // ================= conv2-int from XT0 =================
  #pragma unroll
  for (int rt = 0; rt < 4; ++rt) cI[rt] = (f32x4){0.f, 0.f, 0.f, 0.f};
  #pragma unroll
  for (int kc = 0; kc < 4; ++kc) {
    #pragma unroll
    for (int rt = 0; rt < 4; ++rt) {
      const short8 Ah = *(const short8*)&XT0[((rt * 4 + kc) * 64 + lane) * 8];
      f32x4 c = cI[rt];
      c = __builtin_amdgcn_mfma_f32_16x16x32_bf16(Ah, BIh[kc], c, 0, 0, 0);
      c = __builtin_amdgcn_mfma_f32_16x16x32_bf16(Ah, BIl[kc], c, 0, 0, 0);
      cI[rt] = c;
    }
  }

  // ---- epilogue2 + s2 partials
  #pragma unroll
  for (int rt = 0; rt < 4; ++rt) {
    const float4 dE = *(const float4*)&degsE[rt * 16 + 4 * q];
    const float4 dI = *(const float4*)&degsI[rt * 16 + 4 * q];
    const float dEv[4] = {dE.x, dE.y, dE.z, dE.w};
    const float dIv[4] = {dI.x, dI.y, dI.z, dI.w};
    #pragma unroll
    for (int r = 0; r < 4; ++r) {
      const int row = rt * 16 + q * 4 + r;
      const float i1e = __shfl(s1iE, row);
      const float i1i = __shfl(s1iI, row);
      float ue = cE[rt][r] * i1e + bE2 + dEv[r] * wcE2;
      ue = fmaxf(ue, 0.01f * ue);
      cE[rt][r] = __expf(ue);
      float ui = cI[rt][r] * i1i + bI2 + dIv[r] * wcI2;
      ui = fmaxf(ui, 0.01f * ui);
      cI[rt][r] = __expf(ui);
    }
    #pragma unroll
    for (int r = 0; r < 4; ++r) {
      float te = cE[rt][r], ti = cI[rt][r];
      te += __shfl_xor(te, 1); ti += __shfl_xor(ti, 1);
      te += __shfl_xor(te, 2); ti += __shfl_xor(ti, 2);
      te += __shfl_xor(te, 4); ti += __shfl_xor(ti, 4);
      te += __shfl_xor(te, 8); ti += __shfl_xor(ti, 8);
      if (n == 0) {
        redA[(rt * 16 + q * 4 + r) * 8 + w] = te;
        redB[(rt * 16 + q * 4 + r) * 8 + w] = ti;
      }
    }
  }
  __syncthreads();   // ---- barrier 4: s2 partials visible

  // ---- row-owned s2 inverses + normalize
  float s2iE, s2iI;
  {
    const f32x4 a0 = *(const f32x4*)&redA[lane * 8];
    const f32x4 a1 = *(const f32x4*)&redA[lane * 8 + 4];
    s2iE = frcp(((a0[0] + a0[1]) + (a0[2] + a0[3])) + ((a1[0] + a1[1]) + (a1[2] + a1[3])));
    const f32x4 b0 = *(const f32x4*)&redB[lane * 8];
    const f32x4 b1 = *(const f32x4*)&redB[lane * 8 + 4];
    s2iI = frcp(((b0[0] + b0[1]) + (b0[2] + b0[3])) + ((b1[0] + b1[1]) + (b1[2] + b1[3])));
  }
  #pragma unroll
  for (int rt = 0; rt < 4; ++rt) {
    #pragma unroll
    for (int r = 0; r < 4; ++r) {
      const int row = rt * 16 + q * 4 + r;
      cE[rt][r] *= __shfl(s2iE, row);
      cI[rt][r] *= __shfl(s2iI, row);
    }
  }

  // ---- scatter into XCD-private per-graph sums (masked per-graph reduce)
  {
    float* __restrict__ ezp = ez_sum + (size_t)cp * EZ_STRIDE;
    float* __restrict__ izp = iz_sum + (size_t)cp * EZ_STRIDE;

    if (mbase + 63 >= NN) {
      #pragma unroll
      for (int rt = 0; rt < 4; ++rt)
        #pragma unroll
        for (int r = 0; r < 4; ++r) {
          const int row = rt * 16 + q * 4 + r;
          if (mbase + row >= NN) { cE[rt][r] = 0.f; cI[rt][r] = 0.f; }
        }
    }

    const int g0 = bg[0], g1 = bg[63];
    if (g0 == g1) {
      float se = 0.f, si = 0.f;
      #pragma unroll
      for (int rt = 0; rt < 4; ++rt)
        #pragma unroll
        for (int r = 0; r < 4; ++r) { se += cE[rt][r]; si += cI[rt][r]; }
      se += __shfl_xor(se, 16); si += __shfl_xor(si, 16);
      se += __shfl_xor(se, 32); si += __shfl_xor(si, 32);
      if (q == 0) {
        atomicAdd(&ezp[g0 * FD + j], se);
        atomicAdd(&izp[g0 * FD + j], si);
      }
    } else {
      for (int g = g0; g <= g1; ++g) {
        float se = 0.f, si = 0.f;
        #pragma unroll
        for (int rt = 0; rt < 4; ++rt)
          #pragma unroll
          for (int r = 0; r < 4; ++r) {
            const int row = rt * 16 + q * 4 + r;
            const bool m = (bg[row] == g);
            se += m ? cE[rt][r] : 0.f;
            si += m ? cI[rt][r] : 0.f;
          }
        se += __shfl_xor(se, 16); si += __shfl_xor(si, 16);
        se += __shfl_xor(se, 32); si += __shfl_xor(si, 32);
        if (q == 0) {
          atomicAdd(&ezp[g * FD + j], se);
          atomicAdd(&izp[g * FD + j], si);
        }
      }
    }
  }
#undef LOADB
}

// =========================================================================
// FALLBACK path (R12 verbatim): used only if cooperative launch can't fit.
// =========================================================================
#define AB_EXT 391
#define AB_INT 196
#define AB_BAT 13
#define AB_PRE 8

__global__ __launch_bounds__(256) void aux_kernel(
    const int4* __restrict__ ei4, const int4* __restrict__ iei4,
    const int* __restrict__ batch,
    const float* __restrict__ wu_e1, const float* __restrict__ wu_e2,
    const float* __restrict__ wu_i1, const float* __restrict__ wu_i2,
    int* __restrict__ deg_ext, int* __restrict__ deg_int, int* __restrict__ cnt,
    unsigned short* __restrict__ WB, float* __restrict__ wcolp, int ncopy)
{
  __shared__ float WS[64 * 129];
  __shared__ int   hb[64];
  const int b = blockIdx.x, t = threadIdx.x;
  const int cp = b & (ncopy - 1);

  if (b < AB_EXT) {
    int* __restrict__ d = deg_ext + (size_t)cp * DEG_STRIDE;
    const int base = b * 512 + t;
    #pragma unroll
    for (int u = 0; u < 2; ++u) {
      const int i = base + u * 256;
      if (i < NE / 4) {
        const int4 v = ei4[i];
        atomicAdd(&d[v.x], 1); atomicAdd(&d[v.y], 1);
        atomicAdd(&d[v.z], 1); atomicAdd(&d[v.w], 1);
      }
    }
  } else if (b < AB_EXT + AB_INT) {
    int* __restrict__ d = deg_int + (size_t)cp * DEG_STRIDE;
    const int base = (b - AB_EXT) * 512 + t;
    #pragma unroll
    for (int u = 0; u < 2; ++u) {
      const int i = base + u * 256;
      if (i < NEI / 4) {
        const int4 v = iei4[i];
        atomicAdd(&d[v.x], 1); atomicAdd(&d[v.y], 1);
        atomicAdd(&d[v.z], 1); atomicAdd(&d[v.w], 1);
      }
    }
  } else if (b < AB_EXT + AB_INT + AB_BAT) {
    if (t < 64) hb[t] = 0;
    __syncthreads();
    const int base = (b - AB_EXT - AB_INT) * 4096 + t;
    for (int u = 0; u < 16; ++u) {
      const int i = base + u * 256;
      if (i < NN) atomicAdd(&hb[batch[i]], 1);
    }
    __syncthreads();
    if (t < 64 && hb[t]) atomicAdd(&cnt[cp * CNT_STRIDE + t], hb[t]);
  } else {
    const int pb = b - AB_EXT - AB_INT - AB_BAT;
    const int c  = pb >> 1;
    const int h  = pb & 1;
    const float* wu = (c == 0) ? wu_e1 : (c == 1) ? wu_e2 : (c == 2) ? wu_i1 : wu_i2;
    for (int idx = t; idx < 64 * 129; idx += 256)
      WS[idx] = wu[(size_t)h * 64 * 129 + idx];
    __syncthreads();
    const int lane = t & 63, u = t >> 6;
    const int n = lane & 15, quad = lane >> 4;
    const int ct = 4 * h + u;
    unsigned short* wb = WB + c * 32768;
    #pragma unroll
    for (int kc = 0; kc < 4; ++kc) {
      const int k0 = kc * 32 + quad * 8;
      const float* src = &WS[(u * 16 + n) * 129 + k0];
      short8 hi, lo;
      #pragma unroll
      for (int e = 0; e < 8; ++e) {
        const float v = src[e];
        const unsigned short hh = bf16h(v);
        hi[e] = (short)hh;
        lo[e] = (short)bf16h(v - bf16tof(hh));
      }
      const int fbase = ((ct * 4 + kc) * 2) * 512 + lane * 8;
      *(short8*)&wb[fbase]       = hi;
      *(short8*)&wb[fbase + 512] = lo;
    }
    if (t < 64) wcolp[c * 128 + h * 64 + t] = WS[t * 129 + 128];
  }
}

__global__ __launch_bounds__(256) void merge_deg_kernel(
    const int* __restrict__ deg_ext, const int* __restrict__ deg_int,
    int* __restrict__ degm, int ncopy)
{
  const int i = blockIdx.x * 256 + threadIdx.x;
  int se = 0, si = 0;
  for (int c = 0; c < ncopy; ++c) {
    se += deg_ext[(size_t)c * DEG_STRIDE + i];
    si += deg_int[(size_t)c * DEG_STRIDE + i];
  }
  degm[i] = se;
  degm[DEG_STRIDE + i] = si;
}

__global__ __launch_bounds__(512, 4) void conv_mfma_kernel(
    const float* __restrict__ x,
    const int* __restrict__ degm,
    const int* __restrict__ batch,
    const unsigned short* __restrict__ WB, const float* __restrict__ wcolp,
    const float* __restrict__ bu_e1, const float* __restrict__ bu_e2,
    const float* __restrict__ bu_i1, const float* __restrict__ bu_i2,
    float* __restrict__ ez_sum, float* __restrict__ iz_sum, int ncopy)
{
  __shared__ unsigned short XT[2][8192];
  __shared__ float degsE[64];
  __shared__ float degsI[64];
  __shared__ int   bg[64];
  __shared__ float redA[64 * 8];
  __shared__ float redB[64 * 8];

  const int tid  = threadIdx.x;
  const int lane = tid & 63;
  const int w    = tid >> 6;
  const int n    = lane & 15;
  const int q    = lane >> 4;
  const int mbase = blockIdx.x * 64;
  const int j = w * 16 + n;
  const int cp = blockIdx.x & (ncopy - 1);

#define LOADB(CONV, BH, BL) do {                                              \
    const unsigned short* _p = WB + (CONV) * 32768 + (w * 4) * 1024 + lane * 8;\
    _Pragma("unroll")                                                          \
    for (int _kc = 0; _kc < 4; ++_kc) {                                        \
      BH[_kc] = *(const short8*)&_p[_kc * 1024];                               \
      BL[_kc] = *(const short8*)&_p[_kc * 1024 + 512];                         \
    }                                                                          \
  } while (0)

  short8 BEh[4], BEl[4], BIh[4], BIl[4];
  LOADB(0, BEh, BEl);
  LOADB(2, BIh, BIl);
  const float wcE1 = wcolp[0 * 128 + j], wcE2 = wcolp[1 * 128 + j];
  const float wcI1 = wcolp[2 * 128 + j], wcI2 = wcolp[3 * 128 + j];
  const float bE1 = bu_e1[j], bE2 = bu_e2[j];
  const float bI1 = bu_i1[j], bI2 = bu_i2[j];

  #pragma unroll
  for (int u = 0; u < 2; ++u) {
    const int oct  = u * 512 + tid;
    const int frag = oct >> 6, l = oct & 63;
    const int row  = (frag >> 2) * 16 + (l & 15);
    const int k0   = (frag & 3) * 32 + (l >> 4) * 8;
    const int node = mbase + row;
    float4 a = make_float4(0.f, 0.f, 0.f, 0.f), bb = a;
    if (node < NN) {
      const float* xr = x + (size_t)node * FD + k0;
      a  = *(const float4*)xr;
      bb = *(const float4*)(xr + 4);
    }
    S8 hi;
    hi.u[0] = pk_bf16(a.x, a.y);
    hi.u[1] = pk_bf16(a.z, a.w);
    hi.u[2] = pk_bf16(bb.x, bb.y);
    hi.u[3] = pk_bf16(bb.z, bb.w);
    *(short8*)&XT[0][oct * 8] = hi.s;
  }
  if (tid < 64) {
    const int node = mbase + tid;
    const bool v = node < NN;
    const int nc = v ? node : (NN - 1);
    degsE[tid] = v ? (float)degm[node] : 0.f;
    degsI[tid] = v ? (float)degm[DEG_STRIDE + node] : 0.f;
    bg[tid]    = batch[nc];
  }
  __syncthreads();

  f32x4 aE[4], aI[4];
  #pragma unroll
  for (int rt = 0; rt < 4; ++rt) {
    aE[rt] = (f32x4){0.f, 0.f, 0.f, 0.f};
    aI[rt] = (f32x4){0.f, 0.f, 0.f, 0.f};
  }
  #pragma unroll
  for (int kc = 0; kc < 4; ++kc) {
    #pragma unroll
    for (int rt = 0; rt < 4; ++rt) {
      const short8 Ah = *(const short8*)&XT[0][((rt * 4 + kc) * 64 + lane) * 8];
      f32x4 ce = aE[rt];
      ce = __builtin_amdgcn_mfma_f32_16x16x32_bf16(Ah, BEh[kc], ce, 0, 0, 0);
      ce = __builtin_amdgcn_mfma_f32_16x16x32_bf16(Ah, BEl[kc], ce, 0, 0, 0);
      aE[rt] = ce;
      f32x4 ci = aI[rt];
      ci = __builtin_amdgcn_mfma_f32_16x16x32_bf16(Ah, BIh[kc], ci, 0, 0, 0);
      ci = __builtin_amdgcn_mfma_f32_16x16x32_bf16(Ah, BIl[kc], ci, 0, 0, 0);
      aI[rt] = ci;
    }
  }

  #pragma unroll
  for (int rt = 0; rt < 4; ++rt) {
    const float4 dE = *(const float4*)&degsE[rt * 16 + 4 * q];
    const float4 dI = *(const float4*)&degsI[rt * 16 + 4 * q];
    const float dEv[4] = {dE.x, dE.y, dE.z, dE.w};
    const float dIv[4] = {dI.x, dI.y, dI.z, dI.w};
    #pragma unroll
    for (int r = 0; r < 4; ++r) {
      float ve = aE[rt][r] + bE1 + dEv[r] * wcE1;
      ve = fmaxf(ve, 0.01f * ve);
      aE[rt][r] = __expf(ve);
      float vi = aI[rt][r] + bI1 + dIv[r] * wcI1;
      vi = fmaxf(vi, 0.01f * vi);
      aI[rt][r] = __expf(vi);
    }
  }

  #pragma unroll
  for (int rt = 0; rt < 4; ++rt) {
    #pragma unroll
    for (int r = 0; r < 4; ++r) {
      float te = aE[rt][r], ti = aI[rt][r];
      te += __shfl_xor(te, 1); ti += __shfl_xor(ti, 1);
      te += __shfl_xor(te, 2); ti += __shfl_xor(ti, 2);
      te += __shfl_xor(te, 4); ti += __shfl_xor(ti, 4);
      te += __shfl_xor(te, 8); ti += __shfl_xor(ti, 8);
      if (n == 0) {
        redA[(rt * 16 + q * 4 + r) * 8 + w] = te;
        redB[(rt * 16 + q * 4 + r) * 8 + w] = ti;
      }
    }
  }

  unsigned int pE[4][2], pI[4][2];
  #pragma unroll
  for (int rt = 0; rt < 4; ++rt) {
    pE[rt][0] = pk_bf16(aE[rt][0], aE[rt][1]);
    pE[rt][1] = pk_bf16(aE[rt][2], aE[rt][3]);
    pI[rt][0] = pk_bf16(aI[rt][0], aI[rt][1]);
    pI[rt][1] = pk_bf16(aI[rt][2], aI[rt][3]);
  }
  LOADB(1, BEh, BEl);
  LOADB(3, BIh, BIl);

  #pragma unroll
  for (int rt = 0; rt < 4; ++rt) {
    const int ib = ((rt * 4 + (w >> 1)) * 64 + ((w & 1) * 2 + (n >> 3)) * 16 + q * 4) * 8 + (n & 7);
    XT[1][ib]      = (unsigned short)(pE[rt][0] & 0xFFFFu);
    XT[1][ib + 8]  = (unsigned short)(pE[rt][0] >> 16);
    XT[1][ib + 16] = (unsigned short)(pE[rt][1] & 0xFFFFu);
    XT[1][ib + 24] = (unsigned short)(pE[rt][1] >> 16);
  }
  __syncthreads();

  #pragma unroll
  for (int rt = 0; rt < 4; ++rt) {
    const int ib = ((rt * 4 + (w >> 1)) * 64 + ((w & 1) * 2 + (n >> 3)) * 16 + q * 4) * 8 + (n & 7);
    XT[0][ib]      = (unsigned short)(pI[rt][0] & 0xFFFFu);
    XT[0][ib + 8]  = (unsigned short)(pI[rt][0] >> 16);
    XT[0][ib + 16] = (unsigned short)(pI[rt][1] & 0xFFFFu);
    XT[0][ib + 24] = (unsigned short)(pI[rt][1] >> 16);
  }

  float s1iE, s1iI;
  {
    const f32x4 a0 = *(const f32x4*)&redA[lane * 8];
    const f32x4 a1 = *(const f32x4*)&redA[lane * 8 + 4];
    s1iE = frcp(((a0[0] + a0[1]) + (a0[2] + a0[3])) + ((a1[0] + a1[1]) + (a1[2] + a1[3])));
    const f32x4 b0 = *(const f32x4*)&redB[lane * 8];
    const f32x4 b1 = *(const f32x4*)&redB[lane * 8 + 4];
    s1iI = frcp(((b0[0] + b0[1]) + (b0[2] + b0[3])) + ((b1[0] + b1[1]) + (b1[2] + b1[3])));
  }

  f32x4 cE[4], cI[4];
  #pragma unroll
  for (int rt = 0; rt < 4; ++rt) cE[rt] = (f32x4){0.f, 0.f, 0.f, 0.f};
  #pragma unroll
  for (int kc = 0; kc < 4; ++kc) {
    #pragma unroll
    for (int rt = 0; rt < 4; ++rt) {
      const short8 Ah = *(const short8*)&XT[1][((rt * 4 + kc) * 64 + lane) * 8];
      f32x4 c = cE[rt];
      c = __builtin_amdgcn_mfma_f32_16x16x32_bf16(Ah, BEh[kc], c, 0, 0, 0);
      c = __builtin_amdgcn_mfma_f32_16x16x32_bf16(Ah, BEl[kc], c, 0, 0, 0);
      cE[rt] = c;
    }
  }
  __syncthreads();

  #pragma unroll
  for (int rt = 0; rt < 4; ++rt) cI[rt] = (f32x4){0.f, 0.f, 0.f, 0.f};
  #pragma unroll
  for (int kc = 0; kc < 4; ++kc) {
    #pragma unroll
    for (int rt = 0; rt < 4; ++rt) {
      const short8 Ah = *(const short8*)&XT[0][((rt * 4 + kc) * 64 + lane) * 8];
      f32x4 c = cI[rt];
      c = __builtin_amdgcn_mfma_f32_16x16x32_bf16(Ah, BIh[kc], c, 0, 0, 0);
      c = __builtin_amdgcn_mfma_f32_16x16x32_bf16(Ah, BIl[kc], c, 0, 0, 0);
      cI[rt] = c;
    }
  }

  #pragma unroll
  for (int rt = 0; rt < 4; ++rt) {
    const float4 dE = *(const float4*)&degsE[rt * 16 + 4 * q];
    const float4 dI = *(const float4*)&degsI[rt * 16 + 4 * q];
    const float dEv[4] = {dE.x, dE.y, dE.z, dE.w};
    const float dIv[4] = {dI.x, dI.y, dI.z, dI.w};
    #pragma unroll
    for (int r = 0; r < 4; ++r) {
      const int row = rt * 16 + q * 4 + r;
      const float i1e = __shfl(s1iE, row);
      const float i1i = __shfl(s1iI, row);
      float ue = cE[rt][r] * i1e + bE2 + dEv[r] * wcE2;
      ue = fmaxf(ue, 0.01f * ue);
      cE[rt][r] = __expf(ue);
      float ui = cI[rt][r] * i1i + bI2 + dIv[r] * wcI2;
      ui = fmaxf(ui, 0.01f * ui);
      cI[rt][r] = __expf(ui);
    }
    #pragma unroll
    for (int r = 0; r < 4; ++r) {
      float te = cE[rt][r], ti = cI[rt][r];
      te += __shfl_xor(te, 1); ti += __shfl_xor(ti, 1);
      te += __shfl_xor(te, 2); ti += __shfl_xor(ti, 2);
      te += __shfl_xor(te, 4); ti += __shfl_xor(ti, 4);
      te += __shfl_xor(te, 8); ti += __shfl_xor(ti, 8);
      if (n == 0) {
        redA[(rt * 16 + q * 4 + r) * 8 + w] = te;
        redB[(rt * 16 + q * 4 + r) * 8 + w] = ti;
      }
    }
  }
  __syncthreads();

  float s2iE, s2iI;
  {
    const f32x4 a0 = *(const f32x4*)&redA[lane * 8];
    const f32x4 a1 = *(const f32x4*)&redA[lane * 8 + 4];
    s2iE = frcp(((a0[0] + a0[1]) + (a0[2] + a0[3])) + ((a1[0] + a1[1]) + (a1[2] + a1[3])));
    const f32x4 b0 = *(const f32x4*)&redB[lane * 8];
    const f32x4 b1 = *(const f32x4*)&redB[lane * 8 + 4];
    s2iI = frcp(((b0[0] + b0[1]) + (b0[2] + b0[3])) + ((b1[0] + b1[1]) + (b1[2] + b1[3])));
  }
  #pragma unroll
  for (int rt = 0; rt < 4; ++rt) {
    #pragma unroll
    for (int r = 0; r < 4; ++r) {
      const int row = rt * 16 + q * 4 + r;
      cE[rt][r] *= __shfl(s2iE, row);
      cI[rt][r] *= __shfl(s2iI, row);
    }
  }

  {
    float* __restrict__ ezp = ez_sum + (size_t)cp * EZ_STRIDE;
    float* __restrict__ izp = iz_sum + (size_t)cp * EZ_STRIDE;

    if (mbase + 63 >= NN) {
      #pragma unroll
      for (int rt = 0; rt < 4; ++rt)
        #pragma unroll
        for (int r = 0; r < 4; ++r) {
          const int row = rt * 16 + q * 4 + r;
          if (mbase + row >= NN) { cE[rt][r] = 0.f; cI[rt][r] = 0.f; }
        }
    }

    const int g0 = bg[0], g1 = bg[63];
    if (g0 == g1) {
      float se = 0.f, si = 0.f;
      #pragma unroll
      for (int rt = 0; rt < 4; ++rt)
        #pragma unroll
        for (int r = 0; r < 4; ++r) { se += cE[rt][r]; si += cI[rt][r]; }
      se += __shfl_xor(se, 16); si += __shfl_xor(si, 16);
      se += __shfl_xor(se, 32); si += __shfl_xor(si, 32);
      if (q == 0) {
        atomicAdd(&ezp[g0 * FD + j], se);
        atomicAdd(&izp[g0 * FD + j], si);
      }
    } else {
      for (int g = g0; g <= g1; ++g) {
        float se = 0.f, si = 0.f;
        #pragma unroll
        for (int rt = 0; rt < 4; ++rt)
          #pragma unroll
          for (int r = 0; r < 4; ++r) {
            const int row = rt * 16 + q * 4 + r;
            const bool m = (bg[row] == g);
            se += m ? cE[rt][r] : 0.f;
            si += m ? cI[rt][r] : 0.f;
          }
        se += __shfl_xor(se, 16); si += __shfl_xor(si, 16);
        se += __shfl_xor(se, 32); si += __shfl_xor(si, 32);
        if (q == 0) {
          atomicAdd(&ezp[g * FD + j], se);
          atomicAdd(&izp[g * FD + j], si);
        }
      }
    }
  }
#undef LOADB
}

// -------------------------------------------------------------------------
// Final MLP: 64 blocks (one per graph) x 128 threads.  Sums ncopy copies.
// -------------------------------------------------------------------------
__global__ __launch_bounds__(128) void fc_kernel(
    const float* __restrict__ ez_sum, const float* __restrict__ iz_sum,
    const int* __restrict__ cnt,
    const float* __restrict__ fc1_w, const float* __restrict__ fc1_b,
    const float* __restrict__ fc2_w, const float* __restrict__ fc2_b,
    float* __restrict__ out, int ncopy)
{
  __shared__ float z[256];
  __shared__ float red2[2];
  const int g = blockIdx.x, t = threadIdx.x;
  int cc = 0;
  float se = 0.f, si = 0.f;
  for (int c = 0; c < ncopy; ++c) {
    cc += cnt[c * CNT_STRIDE + g];
    se += ez_sum[(size_t)c * EZ_STRIDE + g * 128 + t];
    si += iz_sum[(size_t)c * EZ_STRIDE + g * 128 + t];
  }
  const float denom = fmaxf((float)cc, 1.0f);
  z[t]       = se / denom;
  z[128 + t] = si / denom;
  __syncthreads();

  const float* wr = fc1_w + (size_t)t * 256;
  float a = fc1_b[t];
  #pragma unroll 4
  for (int c = 0; c < 256; c += 4) {
    const float4 wv = *(const float4*)(wr + c);
    a += wv.x * z[c] + wv.y * z[c + 1] + wv.z * z[c + 2] + wv.w * z[c + 3];
  }
  a = fmaxf(a, 0.f) * fc2_w[t];
  a += __shfl_xor(a, 1);
  a += __shfl_xor(a, 2);
  a += __shfl_xor(a, 4);
  a += __shfl_xor(a, 8);
  a += __shfl_xor(a, 16);
  a += __shfl_xor(a, 32);
  if ((t & 63) == 0) red2[t >> 6] = a;
  __syncthreads();
  if (t == 0) out[g] = red2[0] + red2[1] + fc2_b[0];
}

// -------------------------------------------------------------------------
extern "C" void kernel_launch(void* const* d_in, const int* in_sizes, int n_in,
                              void* d_out, int out_size, void* d_ws, size_t ws_size,
                              hipStream_t stream) {
  const float* x     = (const float*)d_in[0];
  const int4*  ei4   = (const int4*) d_in[1];   // [2,E]: first E = sources
  const int4*  iei4  = (const int4*) d_in[3];
  const int*   batch = (const int*)  d_in[5];
  const float* wu_e1 = (const float*)d_in[8];
  const float* bu_e1 = (const float*)d_in[9];
  const float* wu_e2 = (const float*)d_in[12];
  const float* bu_e2 = (const float*)d_in[13];
  const float* wu_i1 = (const float*)d_in[16];
  const float* bu_i1 = (const float*)d_in[17];
  const float* wu_i2 = (const float*)d_in[20];
  const float* bu_i2 = (const float*)d_in[21];
  const float* fc1_w = (const float*)d_in[22];
  const float* fc1_b = (const float*)d_in[23];
  const float* fc2_w = (const float*)d_in[24];
  const float* fc2_b = (const float*)d_in[25];

  const size_t need8 = 8ull * (2 * 200704 + 2 * 32768 + 256)
                     + 2 * 200704 + 262144 + 2048;
  const int ncopy = (ws_size >= need8) ? 8 : 1;

  char* ws = (char*)d_ws;
  size_t off = 0;
  int*   deg_ext = (int*)(ws + off);  off += (size_t)ncopy * 200704;
  int*   deg_int = (int*)(ws + off);  off += (size_t)ncopy * 200704;
  float* ez      = (float*)(ws + off); off += (size_t)ncopy * 32768;
  float* iz      = (float*)(ws + off); off += (size_t)ncopy * 32768;
  int*   cnt     = (int*)(ws + off);  off += (size_t)ncopy * 256;
  const size_t zero_bytes = off;
  int*   degm    = (int*)(ws + off);  off += 2 * 200704;   // fallback only
  unsigned short* WB = (unsigned short*)(ws + off); off += 262144;
  float* wcolp   = (float*)(ws + off); off += 2048;

  hipMemsetAsync(d_ws, 0, zero_bytes, stream);

  // cooperative capacity precheck: need all NB blocks co-resident
  int maxB = 0;
  (void)hipOccupancyMaxActiveBlocksPerMultiprocessor(
      &maxB, reinterpret_cast<const void*>(fused_kernel), 512, 0);
  bool coop = (maxB > 0) && ((long long)maxB * 256 >= NB) && (ncopy == 8);

  if (coop) {
    int ncopy_v = ncopy;
    void* kargs[] = {
      (void*)&x, (void*)&ei4, (void*)&iei4, (void*)&batch,
      (void*)&wu_e1, (void*)&wu_e2, (void*)&wu_i1, (void*)&wu_i2,
      (void*)&deg_ext, (void*)&deg_int, (void*)&cnt,
      (void*)&WB, (void*)&wcolp,
      (void*)&bu_e1, (void*)&bu_e2, (void*)&bu_i1, (void*)&bu_i2,
      (void*)&ez, (void*)&iz, (void*)&ncopy_v
    };
    hipError_t rc = hipLaunchCooperativeKernel(
        reinterpret_cast<const void*>(fused_kernel),
        dim3(NB), dim3(512), kargs, 0, stream);
    coop = (rc == hipSuccess);
  }

  if (!coop) {
    // fallback: proven R12 4-dispatch path
    aux_kernel<<<AB_EXT + AB_INT + AB_BAT + AB_PRE, 256, 0, stream>>>(
        ei4, iei4, batch, wu_e1, wu_e2, wu_i1, wu_i2,
        deg_ext, deg_int, cnt, WB, wcolp, ncopy);
    merge_deg_kernel<<<DEG_STRIDE / 256, 256, 0, stream>>>(
        deg_ext, deg_int, degm, ncopy);
    conv_mfma_kernel<<<dim3(NB), 512, 0, stream>>>(
        x, degm, batch, WB, wcolp,
        bu_e1, bu_e2, bu_i1, bu_i2, ez, iz, ncopy);
  }

  fc_kernel<<<NG, 128, 0, stream>>>(ez, iz, cnt, fc1_w, fc1_b, fc2_w, fc2_b,
                                    (float*)d_out, ncopy);
}

// Round 9
// 224.574 us; speedup vs baseline: 1.5417x; 1.0131x over previous
//
#include <hip/hip_runtime.h>
#include <hip/hip_bf16.h>

// Problem constants
#define NN  50000   // nodes
#define FD  128     // features
#define NE  800000  // external edges
#define NEI 400000  // internal edges
#define NG  64      // graphs

// Per-copy strides (in elements) for XCD-privatized accumulators
#define DEG_STRIDE 50176     // ints  (200704 B per copy)
#define EZ_STRIDE  8192      // floats (32768 B per copy)
#define CNT_STRIDE 64        // ints   (256 B per copy)

typedef short  short8 __attribute__((ext_vector_type(8)));
typedef float  f32x4  __attribute__((ext_vector_type(4)));

union S8 { short8 s; unsigned int u[4]; };

__device__ __forceinline__ unsigned short bf16h(float f) {
  unsigned int u = __float_as_uint(f);
  u += 0x7FFFu + ((u >> 16) & 1u);            // RNE
  return (unsigned short)(u >> 16);
}
__device__ __forceinline__ float bf16tof(unsigned short h) {
  return __uint_as_float(((unsigned int)h) << 16);
}
// packed 2xf32 -> 2xbf16 (v_cvt_pk_bf16_f32): a in low 16, b in high 16
__device__ __forceinline__ unsigned int pk_bf16(float a, float b) {
  __hip_bfloat162 h = __float22bfloat162_rn(make_float2(a, b));
  unsigned int u;
  __builtin_memcpy(&u, &h, 4);
  return u;
}
// fast reciprocal: v_rcp_f32 (~1 ulp) — tolerance is 4.2e-5, plenty of slack
__device__ __forceinline__ float frcp(float x) { return __builtin_amdgcn_rcpf(x); }

// -------------------------------------------------------------------------
// ONE aux dispatch (R11 structure, proven).  Atomic targets XCD-privatized:
// copy = blockIdx & (ncopy-1).
// -------------------------------------------------------------------------
#define AB_EXT 391
#define AB_INT 196
#define AB_BAT 13
#define AB_PRE 8

__global__ __launch_bounds__(256) void aux_kernel(
    const int4* __restrict__ ei4, const int4* __restrict__ iei4,
    const int* __restrict__ batch,
    const float* __restrict__ wu_e1, const float* __restrict__ wu_e2,
    const float* __restrict__ wu_i1, const float* __restrict__ wu_i2,
    int* __restrict__ deg_ext, int* __restrict__ deg_int, int* __restrict__ cnt,
    unsigned short* __restrict__ WB, float* __restrict__ wcolp, int ncopy)
{
  __shared__ float WS[64 * 129];
  __shared__ int   hb[64];
  const int b = blockIdx.x, t = threadIdx.x;
  const int cp = b & (ncopy - 1);

  if (b < AB_EXT) {
    int* __restrict__ d = deg_ext + (size_t)cp * DEG_STRIDE;
    const int base = b * 512 + t;
    #pragma unroll
    for (int u = 0; u < 2; ++u) {
      const int i = base + u * 256;
      if (i < NE / 4) {
        const int4 v = ei4[i];
        atomicAdd(&d[v.x], 1);
        atomicAdd(&d[v.y], 1);
        atomicAdd(&d[v.z], 1);
        atomicAdd(&d[v.w], 1);
      }
    }
  } else if (b < AB_EXT + AB_INT) {
    int* __restrict__ d = deg_int + (size_t)cp * DEG_STRIDE;
    const int base = (b - AB_EXT) * 512 + t;
    #pragma unroll
    for (int u = 0; u < 2; ++u) {
      const int i = base + u * 256;
      if (i < NEI / 4) {
        const int4 v = iei4[i];
        atomicAdd(&d[v.x], 1);
        atomicAdd(&d[v.y], 1);
        atomicAdd(&d[v.z], 1);
        atomicAdd(&d[v.w], 1);
      }
    }
  } else if (b < AB_EXT + AB_INT + AB_BAT) {
    if (t < 64) hb[t] = 0;
    __syncthreads();
    const int base = (b - AB_EXT - AB_INT) * 4096 + t;
    for (int u = 0; u < 16; ++u) {
      const int i = base + u * 256;
      if (i < NN) atomicAdd(&hb[batch[i]], 1);
    }
    __syncthreads();
    if (t < 64 && hb[t]) atomicAdd(&cnt[cp * CNT_STRIDE + t], hb[t]);
  } else {
    const int pb = b - AB_EXT - AB_INT - AB_BAT;   // 0..7
    const int c  = pb >> 1;                         // conv 0..3
    const int h  = pb & 1;                          // row half
    const float* wu = (c == 0) ? wu_e1 : (c == 1) ? wu_e2 : (c == 2) ? wu_i1 : wu_i2;
    for (int idx = t; idx < 64 * 129; idx += 256)
      WS[idx] = wu[(size_t)h * 64 * 129 + idx];
    __syncthreads();
    const int lane = t & 63, u = t >> 6;
    const int n = lane & 15, quad = lane >> 4;
    const int ct = 4 * h + u;
    unsigned short* wb = WB + c * 32768;
    #pragma unroll
    for (int kc = 0; kc < 4; ++kc) {
      const int k0 = kc * 32 + quad * 8;
      const float* src = &WS[(u * 16 + n) * 129 + k0];
      short8 hi, lo;
      #pragma unroll
      for (int e = 0; e < 8; ++e) {
        const float v = src[e];
        const unsigned short hh = bf16h(v);
        hi[e] = (short)hh;
        lo[e] = (short)bf16h(v - bf16tof(hh));
      }
      const int fbase = ((ct * 4 + kc) * 2) * 512 + lane * 8;
      *(short8*)&wb[fbase]       = hi;
      *(short8*)&wb[fbase + 512] = lo;
    }
    if (t < 64) wcolp[c * 128 + h * 64 + t] = WS[t * 129 + 128];
  }
}

// -------------------------------------------------------------------------
// Merge of the ncopy privatized degree histograms into ONE array (R12).
// degm layout: [0, DEG_STRIDE) = ext, [DEG_STRIDE, 2*DEG_STRIDE) = int.
// -------------------------------------------------------------------------
__global__ __launch_bounds__(256) void merge_deg_kernel(
    const int* __restrict__ deg_ext, const int* __restrict__ deg_int,
    int* __restrict__ degm, int ncopy)
{
  const int i = blockIdx.x * 256 + threadIdx.x;   // grid covers DEG_STRIDE
  int se = 0, si = 0;
  for (int c = 0; c < ncopy; ++c) {
    se += deg_ext[(size_t)c * DEG_STRIDE + i];
    si += deg_int[(size_t)c * DEG_STRIDE + i];
  }
  degm[i] = se;
  degm[DEG_STRIDE + i] = si;
}

// -------------------------------------------------------------------------
// Fused conv chain (merged ext+int, R12 structure).  R16/R17 delta: B loads
// are PER-KC with 2-deep ping-pong prefetch instead of 4-kc upfront.
// Live B state drops 64 -> 32 VGPR (conv1) / 16 (conv2).  Rationale: gfx950
// unified VGPR/AGPR file — R12's 64 arch-VGPR (rocprof excludes AGPR)
// + 32 AGPR acc + temps crossed the 128-reg occupancy cliff -> 8 waves/CU
// = 1 block/CU = the measured 26% occupancy plateau.  Target <=128 total
// -> 2 blocks/CU.  (R17 = R16 resubmitted: R16's bench error is attributed
// to the node wedged by R15's spin-barrier deadlock; this kernel has no
// spin/coop constructs and its skeleton passed 4 prior rounds.)
// -------------------------------------------------------------------------
__global__ __launch_bounds__(512, 4) void conv_mfma_kernel(
    const float* __restrict__ x,
    const int* __restrict__ degm,
    const int* __restrict__ batch,
    const unsigned short* __restrict__ WB, const float* __restrict__ wcolp,
    const float* __restrict__ bu_e1, const float* __restrict__ bu_e2,
    const float* __restrict__ bu_i1, const float* __restrict__ bu_i2,
    float* __restrict__ ez_sum, float* __restrict__ iz_sum, int ncopy)
{
  __shared__ unsigned short XT[2][8192];   // A fragments (bf16), 2 x 16 KB
  __shared__ float degsE[64];
  __shared__ float degsI[64];
  __shared__ int   bg[64];
  __shared__ float redA[64 * 8];           // [row][wave]: s1e, then s2e
  __shared__ float redB[64 * 8];           // [row][wave]: s1i, then s2i

  const int tid  = threadIdx.x;
  const int lane = tid & 63;
  const int w    = tid >> 6;        // wave = column tile 0..7
  const int n    = lane & 15;
  const int q    = lane >> 4;
  const int mbase = blockIdx.x * 64;
  const int j = w * 16 + n;         // this lane's output column
  const int cp = blockIdx.x & (ncopy - 1);

// Load the 4 fragments {ext-hi, ext-lo, int-hi, int-lo} for one kc of a
// conv stage.  conv stage CONVE in {0,1}; int chain is CONVE+2 (= +65536
// ushorts).  Fragment (conv,ct=w,kc): hi at (w*4+kc)*1024, lo at +512.
#define LOADK4(CONVE, KC, B) do {                                             \
    const unsigned short* _p = WB + (CONVE) * 32768 + (w * 4 + (KC)) * 1024 + lane * 8; \
    B[0] = *(const short8*)&_p[0];     B[1] = *(const short8*)&_p[512];       \
    B[2] = *(const short8*)&_p[65536]; B[3] = *(const short8*)&_p[66048];     \
  } while (0)
// 2-fragment variant (hi,lo of a single conv index CONVV)
#define LOADK2(CONVV, KC, B) do {                                             \
    const unsigned short* _p = WB + (CONVV) * 32768 + (w * 4 + (KC)) * 1024 + lane * 8; \
    B[0] = *(const short8*)&_p[0];     B[1] = *(const short8*)&_p[512];       \
  } while (0)

// One conv1 kc-step: 4 row-tiles x {ext hi+lo, int hi+lo} = 16 MFMAs
#define C1STEP(KC, B) do {                                                    \
    _Pragma("unroll")                                                          \
    for (int rt = 0; rt < 4; ++rt) {                                           \
      const short8 Ah = *(const short8*)&XT[0][((rt * 4 + (KC)) * 64 + lane) * 8]; \
      f32x4 ce = aE[rt];                                                       \
      ce = __builtin_amdgcn_mfma_f32_16x16x32_bf16(Ah, B[0], ce, 0, 0, 0);     \
      ce = __builtin_amdgcn_mfma_f32_16x16x32_bf16(Ah, B[1], ce, 0, 0, 0);     \
      aE[rt] = ce;                                                             \
      f32x4 ci = aI[rt];                                                       \
      ci = __builtin_amdgcn_mfma_f32_16x16x32_bf16(Ah, B[2], ci, 0, 0, 0);     \
      ci = __builtin_amdgcn_mfma_f32_16x16x32_bf16(Ah, B[3], ci, 0, 0, 0);     \
      aI[rt] = ci;                                                             \
    }                                                                          \
  } while (0)

// One conv2 kc-step on XT[XB] into ACC: 4 row-tiles x {hi,lo} = 8 MFMAs
#define C2STEP(XB, KC, B, ACC) do {                                           \
    _Pragma("unroll")                                                          \
    for (int rt = 0; rt < 4; ++rt) {                                           \
      const short8 Ah = *(const short8*)&XT[XB][((rt * 4 + (KC)) * 64 + lane) * 8]; \
      f32x4 c = ACC[rt];                                                       \
      c = __builtin_amdgcn_mfma_f32_16x16x32_bf16(Ah, B[0], c, 0, 0, 0);       \
      c = __builtin_amdgcn_mfma_f32_16x16x32_bf16(Ah, B[1], c, 0, 0, 0);       \
      ACC[rt] = c;                                                             \
    }                                                                          \
  } while (0)

  // ---- early B prefetch: conv1 kc=0,1 (both chains) — 8 loads in flight
  short8 Ba[4], Bb[4];
  LOADK4(0, 0, Ba);
  LOADK4(0, 1, Bb);
  const float wcE1 = wcolp[0 * 128 + j], wcE2 = wcolp[1 * 128 + j];
  const float wcI1 = wcolp[2 * 128 + j], wcI2 = wcolp[3 * 128 + j];
  const float bE1 = bu_e1[j], bE2 = bu_e2[j];
  const float bI1 = bu_i1[j], bI2 = bu_i2[j];

  // ---- stage x -> bf16 A fragments in XT[0], octet-linear (conflict-free)
  #pragma unroll
  for (int u = 0; u < 2; ++u) {
    const int oct  = u * 512 + tid;          // 1024 octets
    const int frag = oct >> 6, l = oct & 63;
    const int row  = (frag >> 2) * 16 + (l & 15);
    const int k0   = (frag & 3) * 32 + (l >> 4) * 8;
    const int node = mbase + row;
    float4 a = make_float4(0.f, 0.f, 0.f, 0.f), bb = a;
    if (node < NN) {
      const float* xr = x + (size_t)node * FD + k0;
      a  = *(const float4*)xr;
      bb = *(const float4*)(xr + 4);
    }
    S8 hi;
    hi.u[0] = pk_bf16(a.x, a.y);
    hi.u[1] = pk_bf16(a.z, a.w);
    hi.u[2] = pk_bf16(bb.x, bb.y);
    hi.u[3] = pk_bf16(bb.z, bb.w);
    *(short8*)&XT[0][oct * 8] = hi.s;
  }
  if (tid < 64) {
    const int node = mbase + tid;
    const bool v = node < NN;
    const int nc = v ? node : (NN - 1);
    degsE[tid] = v ? (float)degm[node] : 0.f;
    degsI[tid] = v ? (float)degm[DEG_STRIDE + node] : 0.f;
    bg[tid]    = batch[nc];       // clamped: invalid rows inherit last graph
  }
  __syncthreads();   // ---- barrier 1: A fragments + degs + bg visible

  // ================= conv1, per-kc B ping-pong ================
  f32x4 aE[4], aI[4];
  #pragma unroll
  for (int rt = 0; rt < 4; ++rt) {
    aE[rt] = (f32x4){0.f, 0.f, 0.f, 0.f};
    aI[rt] = (f32x4){0.f, 0.f, 0.f, 0.f};
  }
  C1STEP(0, Ba);
  LOADK4(0, 2, Ba);     // WAR on Ba: loads issue after step-0 MFMAs read it
  C1STEP(1, Bb);
  LOADK4(0, 3, Bb);
  C1STEP(2, Ba);
  C1STEP(3, Bb);

  // ---- epilogue1 (both chains): E1 = exp(leaky(acc + b + deg*wc)), f32
  #pragma unroll
  for (int rt = 0; rt < 4; ++rt) {
    const float4 dE = *(const float4*)&degsE[rt * 16 + 4 * q];
    const float4 dI = *(const float4*)&degsI[rt * 16 + 4 * q];
    const float dEv[4] = {dE.x, dE.y, dE.z, dE.w};
    const float dIv[4] = {dI.x, dI.y, dI.z, dI.w};
    #pragma unroll
    for (int r = 0; r < 4; ++r) {
      float ve = aE[rt][r] + bE1 + dEv[r] * wcE1;
      ve = fmaxf(ve, 0.01f * ve);
      aE[rt][r] = __expf(ve);
      float vi = aI[rt][r] + bI1 + dIv[r] * wcI1;
      vi = fmaxf(vi, 0.01f * vi);
      aI[rt][r] = __expf(vi);
    }
  }

  // ---- s1 partials (exact f32): row-sum over this wave's 16 cols
  #pragma unroll
  for (int rt = 0; rt < 4; ++rt) {
    #pragma unroll
    for (int r = 0; r < 4; ++r) {
      float te = aE[rt][r], ti = aI[rt][r];
      te += __shfl_xor(te, 1); ti += __shfl_xor(ti, 1);
      te += __shfl_xor(te, 2); ti += __shfl_xor(ti, 2);
      te += __shfl_xor(te, 4); ti += __shfl_xor(ti, 4);
      te += __shfl_xor(te, 8); ti += __shfl_xor(ti, 8);
      if (n == 0) {
        redA[(rt * 16 + q * 4 + r) * 8 + w] = te;
        redB[(rt * 16 + q * 4 + r) * 8 + w] = ti;
      }
    }
  }

  // ---- pack E1 to bf16 pairs (regs); prefetch conv2-ext B (kc 0,1) —
  //      latency hides under the pack + XT1 write + barrier 2
  unsigned int pE[4][2], pI[4][2];
  #pragma unroll
  for (int rt = 0; rt < 4; ++rt) {
    pE[rt][0] = pk_bf16(aE[rt][0], aE[rt][1]);
    pE[rt][1] = pk_bf16(aE[rt][2], aE[rt][3]);
    pI[rt][0] = pk_bf16(aI[rt][0], aI[rt][1]);
    pI[rt][1] = pk_bf16(aI[rt][2], aI[rt][3]);
  }
  short8 Ca[2], Cb[2];
  LOADK2(1, 0, Ca);
  LOADK2(1, 1, Cb);

  // ---- write E1e -> XT[1] in A-fragment order (no WAR: XT[1] fresh)
  #pragma unroll
  for (int rt = 0; rt < 4; ++rt) {
    const int ib = ((rt * 4 + (w >> 1)) * 64 + ((w & 1) * 2 + (n >> 3)) * 16 + q * 4) * 8 + (n & 7);
    XT[1][ib]      = (unsigned short)(pE[rt][0] & 0xFFFFu);
    XT[1][ib + 8]  = (unsigned short)(pE[rt][0] >> 16);
    XT[1][ib + 16] = (unsigned short)(pE[rt][1] & 0xFFFFu);
    XT[1][ib + 24] = (unsigned short)(pE[rt][1] >> 16);
  }
  __syncthreads();   // ---- barrier 2: XT1 + s1 partials visible; XT0 reads done

  // ---- write E1i -> XT[0] (safe now)
  #pragma unroll
  for (int rt = 0; rt < 4; ++rt) {
    const int ib = ((rt * 4 + (w >> 1)) * 64 + ((w & 1) * 2 + (n >> 3)) * 16 + q * 4) * 8 + (n & 7);
    XT[0][ib]      = (unsigned short)(pI[rt][0] & 0xFFFFu);
    XT[0][ib + 8]  = (unsigned short)(pI[rt][0] >> 16);
    XT[0][ib + 16] = (unsigned short)(pI[rt][1] & 0xFFFFu);
    XT[0][ib + 24] = (unsigned short)(pI[rt][1] >> 16);
  }

  // ---- row-owned s1 inverses: lane ℓ sums row ℓ (1 rcp per row, not 16)
  float s1iE, s1iI;
  {
    const f32x4 a0 = *(const f32x4*)&redA[lane * 8];
    const f32x4 a1 = *(const f32x4*)&redA[lane * 8 + 4];
    s1iE = frcp(((a0[0] + a0[1]) + (a0[2] + a0[3])) + ((a1[0] + a1[1]) + (a1[2] + a1[3])));
    const f32x4 b0 = *(const f32x4*)&redB[lane * 8];
    const f32x4 b1 = *(const f32x4*)&redB[lane * 8 + 4];
    s1iI = frcp(((b0[0] + b0[1]) + (b0[2] + b0[3])) + ((b1[0] + b1[1]) + (b1[2] + b1[3])));
  }

  // ================= conv2-ext from XT[1], per-kc B ping-pong ============
  f32x4 cE[4], cI[4];
  #pragma unroll
  for (int rt = 0; rt < 4; ++rt) cE[rt] = (f32x4){0.f, 0.f, 0.f, 0.f};
  C2STEP(1, 0, Ca, cE);
  LOADK2(1, 2, Ca);
  C2STEP(1, 1, Cb, cE);
  LOADK2(1, 3, Cb);
  C2STEP(1, 2, Ca, cE);
  LOADK2(3, 0, Ca);     // conv2-int kc0 prefetch (consumed after barrier 3)
  C2STEP(1, 3, Cb, cE);
  LOADK2(3, 1, Cb);
  __syncthreads();   // ---- barrier 3: E1i visible; redA/redB s1-reads done

  // ================= conv2-int from XT[0] =================
  #pragma unroll
  for (int rt = 0; rt < 4; ++rt) cI[rt] = (f32x4){0.f, 0.f, 0.f, 0.f};
  C2STEP(0, 0, Ca, cI);
  LOADK2(3, 2, Ca);
  C2STEP(0, 1, Cb, cI);
  LOADK2(3, 3, Cb);
  C2STEP(0, 2, Ca, cI);
  C2STEP(0, 3, Cb, cI);

  // ---- epilogue2 (both chains): logits = U2*inv_s1 + b + deg*wc;
  //      E2 = exp(leaky(.)); s2 partials -> redA/redB (safe after b3)
  #pragma unroll
  for (int rt = 0; rt < 4; ++rt) {
    const float4 dE = *(const float4*)&degsE[rt * 16 + 4 * q];
    const float4 dI = *(const float4*)&degsI[rt * 16 + 4 * q];
    const float dEv[4] = {dE.x, dE.y, dE.z, dE.w};
    const float dIv[4] = {dI.x, dI.y, dI.z, dI.w};
    #pragma unroll
    for (int r = 0; r < 4; ++r) {
      const int row = rt * 16 + q * 4 + r;
      const float i1e = __shfl(s1iE, row);
      const float i1i = __shfl(s1iI, row);
      float ue = cE[rt][r] * i1e + bE2 + dEv[r] * wcE2;
      ue = fmaxf(ue, 0.01f * ue);
      cE[rt][r] = __expf(ue);
      float ui = cI[rt][r] * i1i + bI2 + dIv[r] * wcI2;
      ui = fmaxf(ui, 0.01f * ui);
      cI[rt][r] = __expf(ui);
    }
    #pragma unroll
    for (int r = 0; r < 4; ++r) {
      float te = cE[rt][r], ti = cI[rt][r];
      te += __shfl_xor(te, 1); ti += __shfl_xor(ti, 1);
      te += __shfl_xor(te, 2); ti += __shfl_xor(ti, 2);
      te += __shfl_xor(te, 4); ti += __shfl_xor(ti, 4);
      te += __shfl_xor(te, 8); ti += __shfl_xor(ti, 8);
      if (n == 0) {
        redA[(rt * 16 + q * 4 + r) * 8 + w] = te;
        redB[(rt * 16 + q * 4 + r) * 8 + w] = ti;
      }
    }
  }
  __syncthreads();   // ---- barrier 4: s2 partials visible

  // ---- row-owned s2 inverses + normalize
  float s2iE, s2iI;
  {
    const f32x4 a0 = *(const f32x4*)&redA[lane * 8];
    const f32x4 a1 = *(const f32x4*)&redA[lane * 8 + 4];
    s2iE = frcp(((a0[0] + a0[1]) + (a0[2] + a0[3])) + ((a1[0] + a1[1]) + (a1[2] + a1[3])));
    const f32x4 b0 = *(const f32x4*)&redB[lane * 8];
    const f32x4 b1 = *(const f32x4*)&redB[lane * 8 + 4];
    s2iI = frcp(((b0[0] + b0[1]) + (b0[2] + b0[3])) + ((b1[0] + b1[1]) + (b1[2] + b1[3])));
  }
  #pragma unroll
  for (int rt = 0; rt < 4; ++rt) {
    #pragma unroll
    for (int r = 0; r < 4; ++r) {
      const int row = rt * 16 + q * 4 + r;
      cE[rt][r] *= __shfl(s2iE, row);
      cI[rt][r] *= __shfl(s2iI, row);
    }
  }

  // ---- scatter into XCD-private per-graph sums (masked per-graph reduce)
  {
    float* __restrict__ ezp = ez_sum + (size_t)cp * EZ_STRIDE;
    float* __restrict__ izp = iz_sum + (size_t)cp * EZ_STRIDE;

    if (mbase + 63 >= NN) {   // zero out-of-range rows (last block only)
      #pragma unroll
      for (int rt = 0; rt < 4; ++rt)
        #pragma unroll
        for (int r = 0; r < 4; ++r) {
          const int row = rt * 16 + q * 4 + r;
          if (mbase + row >= NN) { cE[rt][r] = 0.f; cI[rt][r] = 0.f; }
        }
    }

    const int g0 = bg[0], g1 = bg[63];
    if (g0 == g1) {
      float se = 0.f, si = 0.f;
      #pragma unroll
      for (int rt = 0; rt < 4; ++rt)
        #pragma unroll
        for (int r = 0; r < 4; ++r) { se += cE[rt][r]; si += cI[rt][r]; }
      se += __shfl_xor(se, 16); si += __shfl_xor(si, 16);
      se += __shfl_xor(se, 32); si += __shfl_xor(si, 32);
      if (q == 0) {
        atomicAdd(&ezp[g0 * FD + j], se);
        atomicAdd(&izp[g0 * FD + j], si);
      }
    } else {
      // batch sorted: tile spans [g0,g1], typically 2 graphs
      for (int g = g0; g <= g1; ++g) {
        float se = 0.f, si = 0.f;
        #pragma unroll
        for (int rt = 0; rt < 4; ++rt)
          #pragma unroll
          for (int r = 0; r < 4; ++r) {
            const int row = rt * 16 + q * 4 + r;
            const bool m = (bg[row] == g);
            se += m ? cE[rt][r] : 0.f;
            si += m ? cI[rt][r] : 0.f;
          }
        se += __shfl_xor(se, 16); si += __shfl_xor(si, 16);
        se += __shfl_xor(se, 32); si += __shfl_xor(si, 32);
        if (q == 0) {
          atomicAdd(&ezp[g * FD + j], se);
          atomicAdd(&izp[g * FD + j], si);
        }
      }
    }
  }
#undef LOADK4
#undef LOADK2
#undef C1STEP
#undef C2STEP
}

// -------------------------------------------------------------------------
// Final MLP: 64 blocks (one per graph) x 128 threads.  Sums ncopy
// XCD-private partials for z and cnt.
// -------------------------------------------------------------------------
__global__ __launch_bounds__(128) void fc_kernel(
    const float* __restrict__ ez_sum, const float* __restrict__ iz_sum,
    const int* __restrict__ cnt,
    const float* __restrict__ fc1_w, const float* __restrict__ fc1_b,
    const float* __restrict__ fc2_w, const float* __restrict__ fc2_b,
    float* __restrict__ out, int ncopy)
{
  __shared__ float z[256];
  __shared__ float red2[2];
  const int g = blockIdx.x, t = threadIdx.x;
  int cc = 0;
  float se = 0.f, si = 0.f;
  for (int c = 0; c < ncopy; ++c) {
    cc += cnt[c * CNT_STRIDE + g];
    se += ez_sum[(size_t)c * EZ_STRIDE + g * 128 + t];
    si += iz_sum[(size_t)c * EZ_STRIDE + g * 128 + t];
  }
  const float denom = fmaxf((float)cc, 1.0f);
  z[t]       = se / denom;
  z[128 + t] = si / denom;
  __syncthreads();

  const float* wr = fc1_w + (size_t)t * 256;
  float a = fc1_b[t];
  #pragma unroll 4
  for (int c = 0; c < 256; c += 4) {
    const float4 wv = *(const float4*)(wr + c);
    a += wv.x * z[c] + wv.y * z[c + 1] + wv.z * z[c + 2] + wv.w * z[c + 3];
  }
  a = fmaxf(a, 0.f) * fc2_w[t];
  a += __shfl_xor(a, 1);
  a += __shfl_xor(a, 2);
  a += __shfl_xor(a, 4);
  a += __shfl_xor(a, 8);
  a += __shfl_xor(a, 16);
  a += __shfl_xor(a, 32);
  if ((t & 63) == 0) red2[t >> 6] = a;
  __syncthreads();
  if (t == 0) out[g] = red2[0] + red2[1] + fc2_b[0];
}

// -------------------------------------------------------------------------
extern "C" void kernel_launch(void* const* d_in, const int* in_sizes, int n_in,
                              void* d_out, int out_size, void* d_ws, size_t ws_size,
                              hipStream_t stream) {
  const float* x     = (const float*)d_in[0];
  const int4*  ei4   = (const int4*) d_in[1];   // [2,E]: first E = sources
  const int4*  iei4  = (const int4*) d_in[3];
  const int*   batch = (const int*)  d_in[5];
  const float* wu_e1 = (const float*)d_in[8];
  const float* bu_e1 = (const float*)d_in[9];
  const float* wu_e2 = (const float*)d_in[12];
  const float* bu_e2 = (const float*)d_in[13];
  const float* wu_i1 = (const float*)d_in[16];
  const float* bu_i1 = (const float*)d_in[17];
  const float* wu_i2 = (const float*)d_in[20];
  const float* bu_i2 = (const float*)d_in[21];
  const float* fc1_w = (const float*)d_in[22];
  const float* fc1_b = (const float*)d_in[23];
  const float* fc2_w = (const float*)d_in[24];
  const float* fc2_b = (const float*)d_in[25];

  // Layout: [ncopy x deg_ext][ncopy x deg_int][ncopy x ez][ncopy x iz]
  //         [ncopy x cnt] | (zeroed up to here) | [degm 2x][WB][wcolp]
  const size_t need8 = 8ull * (2 * 200704 + 2 * 32768 + 256)
                     + 2 * 200704 + 262144 + 2048;
  const int ncopy = (ws_size >= need8) ? 8 : 1;

  char* ws = (char*)d_ws;
  size_t off = 0;
  int*   deg_ext = (int*)(ws + off);  off += (size_t)ncopy * 200704;
  int*   deg_int = (int*)(ws + off);  off += (size_t)ncopy * 200704;
  float* ez      = (float*)(ws + off); off += (size_t)ncopy * 32768;
  float* iz      = (float*)(ws + off); off += (size_t)ncopy * 32768;
  int*   cnt     = (int*)(ws + off);  off += (size_t)ncopy * 256;
  const size_t zero_bytes = off;
  int*   degm    = (int*)(ws + off);  off += 2 * 200704;
  unsigned short* WB = (unsigned short*)(ws + off); off += 262144;
  float* wcolp   = (float*)(ws + off); off += 2048;

  hipMemsetAsync(d_ws, 0, zero_bytes, stream);

  aux_kernel<<<AB_EXT + AB_INT + AB_BAT + AB_PRE, 256, 0, stream>>>(
      ei4, iei4, batch, wu_e1, wu_e2, wu_i1, wu_i2,
      deg_ext, deg_int, cnt, WB, wcolp, ncopy);

  merge_deg_kernel<<<DEG_STRIDE / 256, 256, 0, stream>>>(
      deg_ext, deg_int, degm, ncopy);

  conv_mfma_kernel<<<dim3((NN + 63) / 64), 512, 0, stream>>>(
      x, degm, batch, WB, wcolp,
      bu_e1, bu_e2, bu_i1, bu_i2, ez, iz, ncopy);

  fc_kernel<<<NG, 128, 0, stream>>>(ez, iz, cnt, fc1_w, fc1_b, fc2_w, fc2_b,
                                    (float*)d_out, ncopy);
}

// Round 10
// 211.062 us; speedup vs baseline: 1.6404x; 1.0640x over previous
//
#include <hip/hip_runtime.h>
#include <hip/hip_bf16.h>

// Problem constants
#define NN  50000   // nodes
#define FD  128     // features
#define NE  800000  // external edges
#define NEI 400000  // internal edges
#define NG  64      // graphs

// Per-copy strides (in elements) for XCD-privatized accumulators
#define DEG_STRIDE 50176     // ints  (200704 B per copy)
#define EZ_STRIDE  8192      // floats (32768 B per copy)
#define CNT_STRIDE 64        // ints   (256 B per copy)

typedef short  short8 __attribute__((ext_vector_type(8)));
typedef float  f32x4  __attribute__((ext_vector_type(4)));

union S8 { short8 s; unsigned int u[4]; };

__device__ __forceinline__ unsigned short bf16h(float f) {
  unsigned int u = __float_as_uint(f);
  u += 0x7FFFu + ((u >> 16) & 1u);            // RNE
  return (unsigned short)(u >> 16);
}
__device__ __forceinline__ float bf16tof(unsigned short h) {
  return __uint_as_float(((unsigned int)h) << 16);
}
// packed 2xf32 -> 2xbf16 (v_cvt_pk_bf16_f32): a in low 16, b in high 16
__device__ __forceinline__ unsigned int pk_bf16(float a, float b) {
  __hip_bfloat162 h = __float22bfloat162_rn(make_float2(a, b));
  unsigned int u;
  __builtin_memcpy(&u, &h, 4);
  return u;
}
// fast reciprocal: v_rcp_f32 (~1 ulp) — tolerance is 4.2e-5, plenty of slack
__device__ __forceinline__ float frcp(float x) { return __builtin_amdgcn_rcpf(x); }

// -------------------------------------------------------------------------
// ONE aux dispatch (R11 structure, proven).  Atomic targets XCD-privatized:
// copy = blockIdx & (ncopy-1).
// -------------------------------------------------------------------------
#define AB_EXT 391
#define AB_INT 196
#define AB_BAT 13
#define AB_PRE 8

__global__ __launch_bounds__(256) void aux_kernel(
    const int4* __restrict__ ei4, const int4* __restrict__ iei4,
    const int* __restrict__ batch,
    const float* __restrict__ wu_e1, const float* __restrict__ wu_e2,
    const float* __restrict__ wu_i1, const float* __restrict__ wu_i2,
    int* __restrict__ deg_ext, int* __restrict__ deg_int, int* __restrict__ cnt,
    unsigned short* __restrict__ WB, float* __restrict__ wcolp, int ncopy)
{
  __shared__ float WS[64 * 129];
  __shared__ int   hb[64];
  const int b = blockIdx.x, t = threadIdx.x;
  const int cp = b & (ncopy - 1);

  if (b < AB_EXT) {
    int* __restrict__ d = deg_ext + (size_t)cp * DEG_STRIDE;
    const int base = b * 512 + t;
    #pragma unroll
    for (int u = 0; u < 2; ++u) {
      const int i = base + u * 256;
      if (i < NE / 4) {
        const int4 v = ei4[i];
        atomicAdd(&d[v.x], 1);
        atomicAdd(&d[v.y], 1);
        atomicAdd(&d[v.z], 1);
        atomicAdd(&d[v.w], 1);
      }
    }
  } else if (b < AB_EXT + AB_INT) {
    int* __restrict__ d = deg_int + (size_t)cp * DEG_STRIDE;
    const int base = (b - AB_EXT) * 512 + t;
    #pragma unroll
    for (int u = 0; u < 2; ++u) {
      const int i = base + u * 256;
      if (i < NEI / 4) {
        const int4 v = iei4[i];
        atomicAdd(&d[v.x], 1);
        atomicAdd(&d[v.y], 1);
        atomicAdd(&d[v.z], 1);
        atomicAdd(&d[v.w], 1);
      }
    }
  } else if (b < AB_EXT + AB_INT + AB_BAT) {
    if (t < 64) hb[t] = 0;
    __syncthreads();
    const int base = (b - AB_EXT - AB_INT) * 4096 + t;
    for (int u = 0; u < 16; ++u) {
      const int i = base + u * 256;
      if (i < NN) atomicAdd(&hb[batch[i]], 1);
    }
    __syncthreads();
    if (t < 64 && hb[t]) atomicAdd(&cnt[cp * CNT_STRIDE + t], hb[t]);
  } else {
    const int pb = b - AB_EXT - AB_INT - AB_BAT;   // 0..7
    const int c  = pb >> 1;                         // conv 0..3
    const int h  = pb & 1;                          // row half
    const float* wu = (c == 0) ? wu_e1 : (c == 1) ? wu_e2 : (c == 2) ? wu_i1 : wu_i2;
    for (int idx = t; idx < 64 * 129; idx += 256)
      WS[idx] = wu[(size_t)h * 64 * 129 + idx];
    __syncthreads();
    const int lane = t & 63, u = t >> 6;
    const int n = lane & 15, quad = lane >> 4;
    const int ct = 4 * h + u;
    unsigned short* wb = WB + c * 32768;
    #pragma unroll
    for (int kc = 0; kc < 4; ++kc) {
      const int k0 = kc * 32 + quad * 8;
      const float* src = &WS[(u * 16 + n) * 129 + k0];
      short8 hi, lo;
      #pragma unroll
      for (int e = 0; e < 8; ++e) {
        const float v = src[e];
        const unsigned short hh = bf16h(v);
        hi[e] = (short)hh;
        lo[e] = (short)bf16h(v - bf16tof(hh));
      }
      const int fbase = ((ct * 4 + kc) * 2) * 512 + lane * 8;
      *(short8*)&wb[fbase]       = hi;
      *(short8*)&wb[fbase + 512] = lo;
    }
    if (t < 64) wcolp[c * 128 + h * 64 + t] = WS[t * 129 + 128];
  }
}

// -------------------------------------------------------------------------
// Merge of the ncopy privatized degree histograms into ONE array (R12).
// degm layout: [0, DEG_STRIDE) = ext, [DEG_STRIDE, 2*DEG_STRIDE) = int.
// -------------------------------------------------------------------------
__global__ __launch_bounds__(256) void merge_deg_kernel(
    const int* __restrict__ deg_ext, const int* __restrict__ deg_int,
    int* __restrict__ degm, int ncopy)
{
  const int i = blockIdx.x * 256 + threadIdx.x;   // grid covers DEG_STRIDE
  int se = 0, si = 0;
  for (int c = 0; c < ncopy; ++c) {
    se += deg_ext[(size_t)c * DEG_STRIDE + i];
    si += deg_int[(size_t)c * DEG_STRIDE + i];
  }
  degm[i] = se;
  degm[DEG_STRIDE + i] = si;
}

// -------------------------------------------------------------------------
// Fused conv chain — R18: R13's 32-row/256-thread/4-wave geometry (which
// PASSED correctness and doubled occupancy) with the register budget fixed:
// __launch_bounds__(256,4) (VGPR cap 128, est. peak ~116 — no spill, unlike
// R13's (256,6)=85-cap catastrophe), chain-pass-split conv passes (E then I)
// with per-kc ping-pong B so live B = 32 VGPR.  Wave owns ctA=w, ctB=w+4.
// Grid 1563; LDS 17.4 KB; target 4 blocks/CU = 16 waves (2-4x residency).
// -------------------------------------------------------------------------
#define ROWS 32

__global__ __launch_bounds__(256, 4) void conv_mfma_kernel(
    const float* __restrict__ x,
    const int* __restrict__ degm,
    const int* __restrict__ batch,
    const unsigned short* __restrict__ WB, const float* __restrict__ wcolp,
    const float* __restrict__ bu_e1, const float* __restrict__ bu_e2,
    const float* __restrict__ bu_i1, const float* __restrict__ bu_i2,
    float* __restrict__ ez_sum, float* __restrict__ iz_sum, int ncopy)
{
  __shared__ unsigned short XT[2][4096];   // A fragments (bf16), 2 x 8 KB
  __shared__ float degsE[ROWS];
  __shared__ float degsI[ROWS];
  __shared__ int   bg[ROWS];
  __shared__ float redA[ROWS * 4];         // [row][wave]: s1e, then s2e
  __shared__ float redB[ROWS * 4];         // [row][wave]: s1i, then s2i

  const int tid  = threadIdx.x;
  const int lane = tid & 63;
  const int w    = tid >> 6;        // wave 0..3; owns ctA=w, ctB=w+4
  const int n    = lane & 15;
  const int q    = lane >> 4;
  const int mbase = blockIdx.x * ROWS;
  const int cp = blockIdx.x & (ncopy - 1);
  const int jA = w * 16 + n;
  const int jB = (w + 4) * 16 + n;

// Per-kc fragment quad for ONE conv index C: {ctA-hi, ctA-lo, ctB-hi, ctB-lo}
// WB layout: conv c at c*32768; fragment (ct,kc): hi (ct*4+kc)*1024, lo +512.
// ctB = ctA+4 -> +16384.
#define LOADP(C, KC, P) do {                                                  \
    const unsigned short* _p = WB + (C) * 32768 + (w * 4 + (KC)) * 1024 + lane * 8; \
    P[0] = *(const short8*)&_p[0];     P[1] = *(const short8*)&_p[512];       \
    P[2] = *(const short8*)&_p[16384]; P[3] = *(const short8*)&_p[16896];     \
  } while (0)

// One kc-step of a single-chain pass on XT[XB] into ACC[rt][s]
#define PSTEP(XB, KC, P, ACC) do {                                            \
    _Pragma("unroll")                                                          \
    for (int rt = 0; rt < 2; ++rt) {                                           \
      const short8 Ah = *(const short8*)&XT[XB][((rt * 4 + (KC)) * 64 + lane) * 8]; \
      f32x4 c0 = ACC[rt][0];                                                   \
      c0 = __builtin_amdgcn_mfma_f32_16x16x32_bf16(Ah, P[0], c0, 0, 0, 0);     \
      c0 = __builtin_amdgcn_mfma_f32_16x16x32_bf16(Ah, P[1], c0, 0, 0, 0);     \
      ACC[rt][0] = c0;                                                         \
      f32x4 c1 = ACC[rt][1];                                                   \
      c1 = __builtin_amdgcn_mfma_f32_16x16x32_bf16(Ah, P[2], c1, 0, 0, 0);     \
      c1 = __builtin_amdgcn_mfma_f32_16x16x32_bf16(Ah, P[3], c1, 0, 0, 0);     \
      ACC[rt][1] = c1;                                                         \
    }                                                                          \
  } while (0)

// Full 4-kc single-chain pass with ping-pong prefetch (Pa/Pb reused)
#define PASS(XB, C, ACC) do {                                                 \
    PSTEP(XB, 0, Pa, ACC);                                                    \
    LOADP(C, 2, Pa);                                                          \
    PSTEP(XB, 1, Pb, ACC);                                                    \
    LOADP(C, 3, Pb);                                                          \
    PSTEP(XB, 2, Pa, ACC);                                                    \
    PSTEP(XB, 3, Pb, ACC);                                                    \
  } while (0)

  // ---- early B prefetch for conv1-E pass (kc 0,1)
  short8 Pa[4], Pb[4];
  LOADP(0, 0, Pa);
  LOADP(0, 1, Pb);
  const float wcE1A = wcolp[0 * 128 + jA], wcE1B = wcolp[0 * 128 + jB];
  const float wcE2A = wcolp[1 * 128 + jA], wcE2B = wcolp[1 * 128 + jB];
  const float wcI1A = wcolp[2 * 128 + jA], wcI1B = wcolp[2 * 128 + jB];
  const float wcI2A = wcolp[3 * 128 + jA], wcI2B = wcolp[3 * 128 + jB];
  const float bE1A = bu_e1[jA], bE1B = bu_e1[jB];
  const float bE2A = bu_e2[jA], bE2B = bu_e2[jB];
  const float bI1A = bu_i1[jA], bI1B = bu_i1[jB];
  const float bI2A = bu_i2[jA], bI2B = bu_i2[jB];

  // ---- stage x -> bf16 A fragments in XT[0], octet-linear (conflict-free)
  #pragma unroll
  for (int u = 0; u < 2; ++u) {
    const int oct  = u * 256 + tid;          // 512 octets
    const int frag = oct >> 6, l = oct & 63;
    const int row  = (frag >> 2) * 16 + (l & 15);
    const int k0   = (frag & 3) * 32 + (l >> 4) * 8;
    const int node = mbase + row;
    float4 a = make_float4(0.f, 0.f, 0.f, 0.f), bb = a;
    if (node < NN) {
      const float* xr = x + (size_t)node * FD + k0;
      a  = *(const float4*)xr;
      bb = *(const float4*)(xr + 4);
    }
    S8 hi;
    hi.u[0] = pk_bf16(a.x, a.y);
    hi.u[1] = pk_bf16(a.z, a.w);
    hi.u[2] = pk_bf16(bb.x, bb.y);
    hi.u[3] = pk_bf16(bb.z, bb.w);
    *(short8*)&XT[0][oct * 8] = hi.s;
  }
  if (tid < ROWS) {
    const int node = mbase + tid;
    const bool v = node < NN;
    const int nc = v ? node : (NN - 1);
    degsE[tid] = v ? (float)degm[node] : 0.f;
    degsI[tid] = v ? (float)degm[DEG_STRIDE + node] : 0.f;
    bg[tid]    = batch[nc];       // clamped: invalid rows inherit last graph
  }
  __syncthreads();   // ---- barrier 1: A fragments + degs + bg visible

  // ================= conv1: pass E, then pass I (ping-pong B) ============
  f32x4 aE[2][2], aI[2][2];
  #pragma unroll
  for (int rt = 0; rt < 2; ++rt)
    #pragma unroll
    for (int s = 0; s < 2; ++s) {
      aE[rt][s] = (f32x4){0.f, 0.f, 0.f, 0.f};
      aI[rt][s] = (f32x4){0.f, 0.f, 0.f, 0.f};
    }
  PASS(0, 0, aE);          // ext conv1
  LOADP(2, 0, Pa);
  LOADP(2, 1, Pb);
  PASS(0, 2, aI);          // int conv1

  // ---- epilogue1: E1 = exp(leaky(acc + b + deg*wc)), f32
  #pragma unroll
  for (int rt = 0; rt < 2; ++rt) {
    const float4 dE = *(const float4*)&degsE[rt * 16 + 4 * q];
    const float4 dI = *(const float4*)&degsI[rt * 16 + 4 * q];
    const float dEv[4] = {dE.x, dE.y, dE.z, dE.w};
    const float dIv[4] = {dI.x, dI.y, dI.z, dI.w};
    #pragma unroll
    for (int r = 0; r < 4; ++r) {
      float v;
      v = aE[rt][0][r] + bE1A + dEv[r] * wcE1A; v = fmaxf(v, 0.01f * v); aE[rt][0][r] = __expf(v);
      v = aE[rt][1][r] + bE1B + dEv[r] * wcE1B; v = fmaxf(v, 0.01f * v); aE[rt][1][r] = __expf(v);
      v = aI[rt][0][r] + bI1A + dIv[r] * wcI1A; v = fmaxf(v, 0.01f * v); aI[rt][0][r] = __expf(v);
      v = aI[rt][1][r] + bI1B + dIv[r] * wcI1B; v = fmaxf(v, 0.01f * v); aI[rt][1][r] = __expf(v);
    }
  }

  // ---- s1 partials: row-sum over this wave's 32 cols (ctA+ctB)
  #pragma unroll
  for (int rt = 0; rt < 2; ++rt) {
    #pragma unroll
    for (int r = 0; r < 4; ++r) {
      float te = aE[rt][0][r] + aE[rt][1][r];
      float ti = aI[rt][0][r] + aI[rt][1][r];
      te += __shfl_xor(te, 1); ti += __shfl_xor(ti, 1);
      te += __shfl_xor(te, 2); ti += __shfl_xor(ti, 2);
      te += __shfl_xor(te, 4); ti += __shfl_xor(ti, 4);
      te += __shfl_xor(te, 8); ti += __shfl_xor(ti, 8);
      if (n == 0) {
        redA[(rt * 16 + q * 4 + r) * 4 + w] = te;
        redB[(rt * 16 + q * 4 + r) * 4 + w] = ti;
      }
    }
  }

  // ---- pack E1 to bf16 pairs; prefetch conv2-ext B (kc 0,1)
  unsigned int pE[2][2][2], pI[2][2][2];
  #pragma unroll
  for (int rt = 0; rt < 2; ++rt)
    #pragma unroll
    for (int s = 0; s < 2; ++s) {
      pE[rt][s][0] = pk_bf16(aE[rt][s][0], aE[rt][s][1]);
      pE[rt][s][1] = pk_bf16(aE[rt][s][2], aE[rt][s][3]);
      pI[rt][s][0] = pk_bf16(aI[rt][s][0], aI[rt][s][1]);
      pI[rt][s][1] = pk_bf16(aI[rt][s][2], aI[rt][s][3]);
    }
  LOADP(1, 0, Pa);
  LOADP(1, 1, Pb);

  // ---- write E1e -> XT[1] in A-fragment order:
  // col j -> kc' = j>>5 = ct>>1; lane' = ((ct&1)*2 + (n>>3))*16 + q*4 + r
  #pragma unroll
  for (int rt = 0; rt < 2; ++rt)
    #pragma unroll
    for (int s = 0; s < 2; ++s) {
      const int ct = w + s * 4;
      const int ib = ((rt * 4 + (ct >> 1)) * 64 + ((ct & 1) * 2 + (n >> 3)) * 16 + q * 4) * 8 + (n & 7);
      XT[1][ib]      = (unsigned short)(pE[rt][s][0] & 0xFFFFu);
      XT[1][ib + 8]  = (unsigned short)(pE[rt][s][0] >> 16);
      XT[1][ib + 16] = (unsigned short)(pE[rt][s][1] & 0xFFFFu);
      XT[1][ib + 24] = (unsigned short)(pE[rt][s][1] >> 16);
    }
  __syncthreads();   // ---- barrier 2: XT1 + s1 partials visible; XT0 reads done

  // ---- write E1i -> XT[0] (conv1 reads done)
  #pragma unroll
  for (int rt = 0; rt < 2; ++rt)
    #pragma unroll
    for (int s = 0; s < 2; ++s) {
      const int ct = w + s * 4;
      const int ib = ((rt * 4 + (ct >> 1)) * 64 + ((ct & 1) * 2 + (n >> 3)) * 16 + q * 4) * 8 + (n & 7);
      XT[0][ib]      = (unsigned short)(pI[rt][s][0] & 0xFFFFu);
      XT[0][ib + 8]  = (unsigned short)(pI[rt][s][0] >> 16);
      XT[0][ib + 16] = (unsigned short)(pI[rt][s][1] & 0xFFFFu);
      XT[0][ib + 24] = (unsigned short)(pI[rt][s][1] >> 16);
    }

  // ---- row-owned s1 inverses: lane ℓ&31 owns row ℓ&31
  float s1iE, s1iI;
  {
    const int rl = (lane & 31) * 4;
    const f32x4 a0 = *(const f32x4*)&redA[rl];
    s1iE = frcp((a0[0] + a0[1]) + (a0[2] + a0[3]));
    const f32x4 b0 = *(const f32x4*)&redB[rl];
    s1iI = frcp((b0[0] + b0[1]) + (b0[2] + b0[3]));
  }

  // ================= conv2-ext from XT[1] =================
  f32x4 cE[2][2], cI[2][2];
  #pragma unroll
  for (int rt = 0; rt < 2; ++rt)
    #pragma unroll
    for (int s = 0; s < 2; ++s) cE[rt][s] = (f32x4){0.f, 0.f, 0.f, 0.f};
  PASS(1, 1, cE);          // ext conv2 from XT1
  LOADP(3, 0, Pa);         // conv2-int prefetch (consumed after barrier 3)
  LOADP(3, 1, Pb);
  __syncthreads();   // ---- barrier 3: E1i visible; redA/redB s1-reads done

  // ================= conv2-int from XT[0] =================
  #pragma unroll
  for (int rt = 0; rt < 2; ++rt)
    #pragma unroll
    for (int s = 0; s < 2; ++s) cI[rt][s] = (f32x4){0.f, 0.f, 0.f, 0.f};
  PASS(0, 3, cI);          // int conv2 from XT0

  // ---- epilogue2: logits = U2*inv_s1 + b + deg*wc; E2 = exp(leaky(.));
  //      s2 partials -> redA/redB (safe after b3)
  #pragma unroll
  for (int rt = 0; rt < 2; ++rt) {
    const float4 dE = *(const float4*)&degsE[rt * 16 + 4 * q];
    const float4 dI = *(const float4*)&degsI[rt * 16 + 4 * q];
    const float dEv[4] = {dE.x, dE.y, dE.z, dE.w};
    const float dIv[4] = {dI.x, dI.y, dI.z, dI.w};
    #pragma unroll
    for (int r = 0; r < 4; ++r) {
      const int row = rt * 16 + q * 4 + r;
      const float i1e = __shfl(s1iE, row);
      const float i1i = __shfl(s1iI, row);
      float v;
      v = cE[rt][0][r] * i1e + bE2A + dEv[r] * wcE2A; v = fmaxf(v, 0.01f * v); cE[rt][0][r] = __expf(v);
      v = cE[rt][1][r] * i1e + bE2B + dEv[r] * wcE2B; v = fmaxf(v, 0.01f * v); cE[rt][1][r] = __expf(v);
      v = cI[rt][0][r] * i1i + bI2A + dIv[r] * wcI2A; v = fmaxf(v, 0.01f * v); cI[rt][0][r] = __expf(v);
      v = cI[rt][1][r] * i1i + bI2B + dIv[r] * wcI2B; v = fmaxf(v, 0.01f * v); cI[rt][1][r] = __expf(v);
    }
    #pragma unroll
    for (int r = 0; r < 4; ++r) {
      float te = cE[rt][0][r] + cE[rt][1][r];
      float ti = cI[rt][0][r] + cI[rt][1][r];
      te += __shfl_xor(te, 1); ti += __shfl_xor(ti, 1);
      te += __shfl_xor(te, 2); ti += __shfl_xor(ti, 2);
      te += __shfl_xor(te, 4); ti += __shfl_xor(ti, 4);
      te += __shfl_xor(te, 8); ti += __shfl_xor(ti, 8);
      if (n == 0) {
        redA[(rt * 16 + q * 4 + r) * 4 + w] = te;
        redB[(rt * 16 + q * 4 + r) * 4 + w] = ti;
      }
    }
  }
  __syncthreads();   // ---- barrier 4: s2 partials visible

  // ---- row-owned s2 inverses + normalize
  float s2iE, s2iI;
  {
    const int rl = (lane & 31) * 4;
    const f32x4 a0 = *(const f32x4*)&redA[rl];
    s2iE = frcp((a0[0] + a0[1]) + (a0[2] + a0[3]));
    const f32x4 b0 = *(const f32x4*)&redB[rl];
    s2iI = frcp((b0[0] + b0[1]) + (b0[2] + b0[3]));
  }
  #pragma unroll
  for (int rt = 0; rt < 2; ++rt) {
    #pragma unroll
    for (int r = 0; r < 4; ++r) {
      const int row = rt * 16 + q * 4 + r;
      const float i2e = __shfl(s2iE, row);
      const float i2i = __shfl(s2iI, row);
      cE[rt][0][r] *= i2e; cE[rt][1][r] *= i2e;
      cI[rt][0][r] *= i2i; cI[rt][1][r] *= i2i;
    }
  }

  // ---- scatter into XCD-private per-graph sums (masked per-graph reduce)
  {
    float* __restrict__ ezp = ez_sum + (size_t)cp * EZ_STRIDE;
    float* __restrict__ izp = iz_sum + (size_t)cp * EZ_STRIDE;

    if (mbase + ROWS - 1 >= NN) {   // zero out-of-range rows (last block)
      #pragma unroll
      for (int rt = 0; rt < 2; ++rt)
        #pragma unroll
        for (int r = 0; r < 4; ++r) {
          const int row = rt * 16 + q * 4 + r;
          if (mbase + row >= NN) {
            cE[rt][0][r] = 0.f; cE[rt][1][r] = 0.f;
            cI[rt][0][r] = 0.f; cI[rt][1][r] = 0.f;
          }
        }
    }

    const int g0 = bg[0], g1 = bg[ROWS - 1];
    for (int g = g0; g <= g1; ++g) {
      const bool one = (g0 == g1);
      float seA = 0.f, siA = 0.f, seB = 0.f, siB = 0.f;
      #pragma unroll
      for (int rt = 0; rt < 2; ++rt)
        #pragma unroll
        for (int r = 0; r < 4; ++r) {
          const int row = rt * 16 + q * 4 + r;
          const bool m = one || (bg[row] == g);
          seA += m ? cE[rt][0][r] : 0.f;
          seB += m ? cE[rt][1][r] : 0.f;
          siA += m ? cI[rt][0][r] : 0.f;
          siB += m ? cI[rt][1][r] : 0.f;
        }
      seA += __shfl_xor(seA, 16); siA += __shfl_xor(siA, 16);
      seB += __shfl_xor(seB, 16); siB += __shfl_xor(siB, 16);
      seA += __shfl_xor(seA, 32); siA += __shfl_xor(siA, 32);
      seB += __shfl_xor(seB, 32); siB += __shfl_xor(siB, 32);
      if (q == 0) {
        atomicAdd(&ezp[g * FD + jA], seA);
        atomicAdd(&ezp[g * FD + jB], seB);
        atomicAdd(&izp[g * FD + jA], siA);
        atomicAdd(&izp[g * FD + jB], siB);
      }
    }
  }
#undef LOADP
#undef PSTEP
#undef PASS
}

// -------------------------------------------------------------------------
// Final MLP: 64 blocks (one per graph) x 128 threads.  Sums ncopy
// XCD-private partials for z and cnt.
// -------------------------------------------------------------------------
__global__ __launch_bounds__(128) void fc_kernel(
    const float* __restrict__ ez_sum, const float* __restrict__ iz_sum,
    const int* __restrict__ cnt,
    const float* __restrict__ fc1_w, const float* __restrict__ fc1_b,
    const float* __restrict__ fc2_w, const float* __restrict__ fc2_b,
    float* __restrict__ out, int ncopy)
{
  __shared__ float z[256];
  __shared__ float red2[2];
  const int g = blockIdx.x, t = threadIdx.x;
  int cc = 0;
  float se = 0.f, si = 0.f;
  for (int c = 0; c < ncopy; ++c) {
    cc += cnt[c * CNT_STRIDE + g];
    se += ez_sum[(size_t)c * EZ_STRIDE + g * 128 + t];
    si += iz_sum[(size_t)c * EZ_STRIDE + g * 128 + t];
  }
  const float denom = fmaxf((float)cc, 1.0f);
  z[t]       = se / denom;
  z[128 + t] = si / denom;
  __syncthreads();

  const float* wr = fc1_w + (size_t)t * 256;
  float a = fc1_b[t];
  #pragma unroll 4
  for (int c = 0; c < 256; c += 4) {
    const float4 wv = *(const float4*)(wr + c);
    a += wv.x * z[c] + wv.y * z[c + 1] + wv.z * z[c + 2] + wv.w * z[c + 3];
  }
  a = fmaxf(a, 0.f) * fc2_w[t];
  a += __shfl_xor(a, 1);
  a += __shfl_xor(a, 2);
  a += __shfl_xor(a, 4);
  a += __shfl_xor(a, 8);
  a += __shfl_xor(a, 16);
  a += __shfl_xor(a, 32);
  if ((t & 63) == 0) red2[t >> 6] = a;
  __syncthreads();
  if (t == 0) out[g] = red2[0] + red2[1] + fc2_b[0];
}

// -------------------------------------------------------------------------
extern "C" void kernel_launch(void* const* d_in, const int* in_sizes, int n_in,
                              void* d_out, int out_size, void* d_ws, size_t ws_size,
                              hipStream_t stream) {
  const float* x     = (const float*)d_in[0];
  const int4*  ei4   = (const int4*) d_in[1];   // [2,E]: first E = sources
  const int4*  iei4  = (const int4*) d_in[3];
  const int*   batch = (const int*)  d_in[5];
  const float* wu_e1 = (const float*)d_in[8];
  const float* bu_e1 = (const float*)d_in[9];
  const float* wu_e2 = (const float*)d_in[12];
  const float* bu_e2 = (const float*)d_in[13];
  const float* wu_i1 = (const float*)d_in[16];
  const float* bu_i1 = (const float*)d_in[17];
  const float* wu_i2 = (const float*)d_in[20];
  const float* bu_i2 = (const float*)d_in[21];
  const float* fc1_w = (const float*)d_in[22];
  const float* fc1_b = (const float*)d_in[23];
  const float* fc2_w = (const float*)d_in[24];
  const float* fc2_b = (const float*)d_in[25];

  // Layout: [ncopy x deg_ext][ncopy x deg_int][ncopy x ez][ncopy x iz]
  //         [ncopy x cnt] | (zeroed up to here) | [degm 2x][WB][wcolp]
  const size_t need8 = 8ull * (2 * 200704 + 2 * 32768 + 256)
                     + 2 * 200704 + 262144 + 2048;
  const int ncopy = (ws_size >= need8) ? 8 : 1;

  char* ws = (char*)d_ws;
  size_t off = 0;
  int*   deg_ext = (int*)(ws + off);  off += (size_t)ncopy * 200704;
  int*   deg_int = (int*)(ws + off);  off += (size_t)ncopy * 200704;
  float* ez      = (float*)(ws + off); off += (size_t)ncopy * 32768;
  float* iz      = (float*)(ws + off); off += (size_t)ncopy * 32768;
  int*   cnt     = (int*)(ws + off);  off += (size_t)ncopy * 256;
  const size_t zero_bytes = off;
  int*   degm    = (int*)(ws + off);  off += 2 * 200704;
  unsigned short* WB = (unsigned short*)(ws + off); off += 262144;
  float* wcolp   = (float*)(ws + off); off += 2048;

  hipMemsetAsync(d_ws, 0, zero_bytes, stream);

  aux_kernel<<<AB_EXT + AB_INT + AB_BAT + AB_PRE, 256, 0, stream>>>(
      ei4, iei4, batch, wu_e1, wu_e2, wu_i1, wu_i2,
      deg_ext, deg_int, cnt, WB, wcolp, ncopy);

  merge_deg_kernel<<<DEG_STRIDE / 256, 256, 0, stream>>>(
      deg_ext, deg_int, degm, ncopy);

  conv_mfma_kernel<<<dim3((NN + ROWS - 1) / ROWS), 256, 0, stream>>>(
      x, degm, batch, WB, wcolp,
      bu_e1, bu_e2, bu_i1, bu_i2, ez, iz, ncopy);

  fc_kernel<<<NG, 128, 0, stream>>>(ez, iz, cnt, fc1_w, fc1_b, fc2_w, fc2_b,
                                    (float*)d_out, ncopy);
}